// Round 8
// baseline (739.052 us; speedup 1.0000x reference)
//
#include <hip/hip_runtime.h>
#include <cmath>

#define N_NODES 50000
#define E_EDGES 800000
#define HID 128
#define HEADS 4
#define HD 32
#define EDIM 16
#define EGD 32
#define VSTRIDE 136   // ushorts per staged V row (272B)
#define SCAN_BS 512
#define SCAN_NB ((N_NODES + SCAN_BS - 1) / SCAN_BS)

typedef __attribute__((ext_vector_type(8))) short bf16x8;
typedef __attribute__((ext_vector_type(4))) float f32x4;

__device__ __forceinline__ float gelu_f(float z) {
    return 0.5f * z * (1.0f + erff(z * 0.7071067811865476f));
}
__device__ __forceinline__ float sigmoid_fast(float z) {
    return __builtin_amdgcn_rcpf(1.0f + __expf(-z));
}
__device__ __forceinline__ short f2bf(float f) {
    unsigned u = __float_as_uint(f);
    unsigned r = u + 0x7fffu + ((u >> 16) & 1u);
    return (short)(r >> 16);
}
__device__ __forceinline__ float bf2f(unsigned short u) {
    return __uint_as_float(((unsigned)u) << 16);
}
__device__ __forceinline__ ushort4 f4bf(float4 v) {
    ushort4 r;
    r.x = (unsigned short)f2bf(v.x); r.y = (unsigned short)f2bf(v.y);
    r.z = (unsigned short)f2bf(v.z); r.w = (unsigned short)f2bf(v.w);
    return r;
}

// ---------------- K0w: weights -> bf16, k4-interleaved [(k>>2)*N+n]*4+(k&3) ----------------
__global__ void __launch_bounds__(256) k0w_conv(
    const float* __restrict__ Wq, const float* __restrict__ Wk, const float* __restrict__ Wv,
    const float* __restrict__ Wo, const float* __restrict__ Wf1, const float* __restrict__ Wf2,
    unsigned short* __restrict__ Wqb4, unsigned short* __restrict__ Wkb4,
    unsigned short* __restrict__ Wvb4, unsigned short* __restrict__ Wob4,
    unsigned short* __restrict__ Wf1b4, unsigned short* __restrict__ Wf2b4)
{
    const int b = blockIdx.x, t = threadIdx.x;
    const float* src; unsigned short* dst; int idx; bool wide;
    if (b < 64)       { src = Wq;  dst = Wqb4;  idx = b * 256 + t;         wide = false; }
    else if (b < 128) { src = Wk;  dst = Wkb4;  idx = (b - 64) * 256 + t;  wide = false; }
    else if (b < 192) { src = Wv;  dst = Wvb4;  idx = (b - 128) * 256 + t; wide = false; }
    else if (b < 256) { src = Wo;  dst = Wob4;  idx = (b - 192) * 256 + t; wide = false; }
    else if (b < 384) { src = Wf1; dst = Wf1b4; idx = (b - 256) * 256 + t; wide = true;  }
    else              { src = Wf2; dst = Wf2b4; idx = (b - 384) * 256 + t; wide = false; }
    int k, n, N;
    if (wide) { k = idx >> 8; n = idx & 255; N = 256; }
    else      { k = idx >> 7; n = idx & 127; N = 128; }
    dst[((size_t)(k >> 2) * N + n) * 4 + (k & 3)] = (unsigned short)f2bf(src[idx]);
}

// ---------------- K1: LN1 + QKV (16 rows / 256 threads, bf16 weights) ----------------
__global__ void __launch_bounds__(256) k1_ln_qkv(
    const float* __restrict__ x, const float* __restrict__ g1, const float* __restrict__ b1,
    const unsigned short* __restrict__ Wqb4, const unsigned short* __restrict__ Wkb4,
    const unsigned short* __restrict__ Wvb4,
    unsigned short* __restrict__ Qb, unsigned short* __restrict__ Kb,
    unsigned short* __restrict__ Vb)
{
    __shared__ float xsm[16][HID];
    const int t = threadIdx.x;
    const int base = blockIdx.x * 16;
    // stage 16 rows of x
    {
        const float4* src = (const float4*)(x + (size_t)base * HID);
        float4* dst = (float4*)xsm;
        dst[t] = src[t];
        dst[t + 256] = src[t + 256];
    }
    __syncthreads();
    // LN stats: thread (row=t>>4, sl=t&15)
    {
        const int sr = t >> 4, sl = t & 15;
        float s1 = 0.f, s2 = 0.f;
        float v[8];
        #pragma unroll
        for (int j = 0; j < 8; ++j) {
            v[j] = xsm[sr][sl + 16 * j];
            s1 += v[j]; s2 += v[j] * v[j];
        }
        #pragma unroll
        for (int m = 1; m < 16; m <<= 1) { s1 += __shfl_xor(s1, m); s2 += __shfl_xor(s2, m); }
        const float mu = s1 * (1.0f / HID);
        const float var = s2 * (1.0f / HID) - mu * mu;
        const float rstd = rsqrtf(var + 1e-5f);
        #pragma unroll
        for (int j = 0; j < 8; ++j) {
            const int col = sl + 16 * j;
            xsm[sr][col] = (v[j] - mu) * rstd * g1[col] + b1[col];
        }
    }
    __syncthreads();
    // GEMM: col c, half h -> rows h*8..h*8+8
    const int c = t & 127, h = t >> 7, r0 = h * 8;
    float aq[8], ak[8], av[8];
    #pragma unroll
    for (int r = 0; r < 8; ++r) { aq[r] = 0.f; ak[r] = 0.f; av[r] = 0.f; }
    for (int k4 = 0; k4 < 32; ++k4) {
        const ushort4 wq4 = ((const ushort4*)Wqb4)[k4 * HID + c];
        const ushort4 wk4 = ((const ushort4*)Wkb4)[k4 * HID + c];
        const ushort4 wv4 = ((const ushort4*)Wvb4)[k4 * HID + c];
        const float q0 = bf2f(wq4.x), q1 = bf2f(wq4.y), q2 = bf2f(wq4.z), q3 = bf2f(wq4.w);
        const float k0 = bf2f(wk4.x), k1v = bf2f(wk4.y), k2 = bf2f(wk4.z), k3 = bf2f(wk4.w);
        const float v0 = bf2f(wv4.x), v1 = bf2f(wv4.y), v2 = bf2f(wv4.z), v3 = bf2f(wv4.w);
        #pragma unroll
        for (int r = 0; r < 8; ++r) {
            const float4 a = *(const float4*)&xsm[r0 + r][k4 * 4];
            aq[r] = fmaf(a.x, q0, aq[r]); aq[r] = fmaf(a.y, q1, aq[r]);
            aq[r] = fmaf(a.z, q2, aq[r]); aq[r] = fmaf(a.w, q3, aq[r]);
            ak[r] = fmaf(a.x, k0, ak[r]); ak[r] = fmaf(a.y, k1v, ak[r]);
            ak[r] = fmaf(a.z, k2, ak[r]); ak[r] = fmaf(a.w, k3, ak[r]);
            av[r] = fmaf(a.x, v0, av[r]); av[r] = fmaf(a.y, v1, av[r]);
            av[r] = fmaf(a.z, v2, av[r]); av[r] = fmaf(a.w, v3, av[r]);
        }
    }
    #pragma unroll
    for (int r = 0; r < 8; ++r) {
        const size_t idx = (size_t)(base + r0 + r) * HID + c;
        Qb[idx] = (unsigned short)f2bf(aq[r]);
        Kb[idx] = (unsigned short)f2bf(ak[r]);
        Vb[idx] = (unsigned short)f2bf(av[r]);
    }
}

// ---------------- CSR build ----------------
__global__ void __launch_bounds__(256) k0a_degree(
    const int* __restrict__ ei, int* __restrict__ deg)
{
    const int e = blockIdx.x * 256 + threadIdx.x;
    atomicAdd(deg + ei[E_EDGES + e], 1);
}

__global__ void __launch_bounds__(SCAN_BS) k0b_scan1(
    const int* __restrict__ deg, int* __restrict__ rowptr, int* __restrict__ bsum)
{
    __shared__ int sm[SCAN_BS];
    const int t = threadIdx.x;
    const int i = blockIdx.x * SCAN_BS + t;
    const int v = (i < N_NODES) ? deg[i] : 0;
    sm[t] = v;
    __syncthreads();
    #pragma unroll
    for (int off = 1; off < SCAN_BS; off <<= 1) {
        int add = (t >= off) ? sm[t - off] : 0;
        __syncthreads();
        sm[t] += add;
        __syncthreads();
    }
    if (i < N_NODES) rowptr[i] = sm[t] - v;
    if (t == SCAN_BS - 1) bsum[blockIdx.x] = sm[t];
}

__global__ void __launch_bounds__(128) k0c_scan2(int* __restrict__ bsum)
{
    __shared__ int sm[128];
    const int t = threadIdx.x;
    const int v = (t < SCAN_NB) ? bsum[t] : 0;
    sm[t] = v;
    __syncthreads();
    #pragma unroll
    for (int off = 1; off < 128; off <<= 1) {
        int add = (t >= off) ? sm[t - off] : 0;
        __syncthreads();
        sm[t] += add;
        __syncthreads();
    }
    if (t < SCAN_NB) bsum[t] = sm[t] - v; // exclusive
}

__global__ void __launch_bounds__(SCAN_BS) k0d_fixup(
    int* __restrict__ rowptr, int* __restrict__ wptr, const int* __restrict__ bsum)
{
    const int i = blockIdx.x * SCAN_BS + threadIdx.x;
    if (i < N_NODES) {
        int r = rowptr[i] + bsum[blockIdx.x];
        rowptr[i] = r;
        wptr[i] = r;
    }
    if (i == 0) rowptr[N_NODES] = E_EDGES;
}

__global__ void __launch_bounds__(256) k0e_scatter(
    const int* __restrict__ ei, int* __restrict__ wptr,
    int* __restrict__ eidx, int* __restrict__ esrc, int* __restrict__ pdst)
{
    const int e = blockIdx.x * 256 + threadIdx.x;
    const int d = ei[E_EDGES + e];
    const int pos = atomicAdd(wptr + d, 1);
    eidx[pos] = e;
    esrc[pos] = ei[e];
    pdst[pos] = d;
}

// ---------------- K2: bf16 QK^T dot + edge-bias MLP + atomicMax + eab emit ----------------
__global__ void __launch_bounds__(256) k2_fused(
    const int* __restrict__ eidx, const int* __restrict__ esrc, const int* __restrict__ pdst,
    const unsigned short* __restrict__ Qb, const unsigned short* __restrict__ Kb,
    const float* __restrict__ ea,
    const float* __restrict__ Wea1, const float* __restrict__ bea1,
    const float* __restrict__ Wea2, const float* __restrict__ bea2,
    float* __restrict__ logits, float* __restrict__ mbuf,
    unsigned short* __restrict__ eab)
{
    const int t = threadIdx.x;
    const int p = (blockIdx.x * 256 + t) >> 5;
    const int s = t & 31;
    const int e = eidx[p];
    const int src = esrc[p];
    const int dst = pdst[p];
    const ushort4 qu = ((const ushort4*)(Qb + (size_t)dst * HID))[s];
    const ushort4 ku = ((const ushort4*)(Kb + (size_t)src * HID))[s];
    float pr = bf2f(qu.x) * bf2f(ku.x) + bf2f(qu.y) * bf2f(ku.y)
             + bf2f(qu.z) * bf2f(ku.z) + bf2f(qu.w) * bf2f(ku.w);
    pr += __shfl_xor(pr, 1);
    pr += __shfl_xor(pr, 2);
    pr += __shfl_xor(pr, 4);
    const float4* eap = (const float4*)(ea + (size_t)e * EDIM);
    float4 a0 = eap[0], a1 = eap[1], a2 = eap[2], a3 = eap[3];
    if (s < 4) {
        const float4 av = (s == 0) ? a0 : (s == 1) ? a1 : (s == 2) ? a2 : a3;
        ((ushort4*)(eab + (size_t)p * EDIM))[s] = f4bf(av);
    }
    float h = bea1[s];
    h = fmaf(a0.x, Wea1[0 * EGD + s], h);  h = fmaf(a0.y, Wea1[1 * EGD + s], h);
    h = fmaf(a0.z, Wea1[2 * EGD + s], h);  h = fmaf(a0.w, Wea1[3 * EGD + s], h);
    h = fmaf(a1.x, Wea1[4 * EGD + s], h);  h = fmaf(a1.y, Wea1[5 * EGD + s], h);
    h = fmaf(a1.z, Wea1[6 * EGD + s], h);  h = fmaf(a1.w, Wea1[7 * EGD + s], h);
    h = fmaf(a2.x, Wea1[8 * EGD + s], h);  h = fmaf(a2.y, Wea1[9 * EGD + s], h);
    h = fmaf(a2.z, Wea1[10 * EGD + s], h); h = fmaf(a2.w, Wea1[11 * EGD + s], h);
    h = fmaf(a3.x, Wea1[12 * EGD + s], h); h = fmaf(a3.y, Wea1[13 * EGD + s], h);
    h = fmaf(a3.z, Wea1[14 * EGD + s], h); h = fmaf(a3.w, Wea1[15 * EGD + s], h);
    h = gelu_f(h);
    const float4 w2 = ((const float4*)Wea2)[s];
    float b0 = h * w2.x, b1 = h * w2.y, b2 = h * w2.z, b3 = h * w2.w;
    #pragma unroll
    for (int off = 1; off < 32; off <<= 1) {
        b0 += __shfl_xor(b0, off);
        b1 += __shfl_xor(b1, off);
        b2 += __shfl_xor(b2, off);
        b3 += __shfl_xor(b3, off);
    }
    const float dv = __shfl(pr, (t & 32) + ((s & 3) << 3));
    if (s < 4) {
        const float bias = (s == 0) ? b0 : (s == 1) ? b1 : (s == 2) ? b2 : b3;
        const float lg = dv * 0.17677669529663689f + bias + bea2[s];
        logits[(size_t)p * 4 + s] = lg;
        if (lg > 0.f) atomicMax((int*)mbuf + (size_t)dst * 4 + s, __float_as_int(lg));
    }
}

// ---------------- K3: el = exp(logit - m); segmented-scan + one atomic per run ----------------
__global__ void __launch_bounds__(256) k3_exp_sum(
    const int* __restrict__ pdst, const float* __restrict__ mbuf,
    float* __restrict__ logits, float* __restrict__ sbuf)
{
    const int p = blockIdx.x * 256 + threadIdx.x;
    const int lane = threadIdx.x & 63;
    const int d = pdst[p];
    float4 lg = *(const float4*)(logits + (size_t)p * 4);
    const float4 mv = *(const float4*)(mbuf + (size_t)d * 4);
    lg.x = __expf(lg.x - mv.x);
    lg.y = __expf(lg.y - mv.y);
    lg.z = __expf(lg.z - mv.z);
    lg.w = __expf(lg.w - mv.w);
    *(float4*)(logits + (size_t)p * 4) = lg;
    float4 v = lg;
    #pragma unroll
    for (int off = 1; off < 64; off <<= 1) {
        const int du = __shfl_up(d, off);
        const float ux = __shfl_up(v.x, off);
        const float uy = __shfl_up(v.y, off);
        const float uz = __shfl_up(v.z, off);
        const float uw = __shfl_up(v.w, off);
        if (lane >= off && du == d) { v.x += ux; v.y += uy; v.z += uz; v.w += uw; }
    }
    const int dn = __shfl_down(d, 1);
    if (lane == 63 || dn != d) {
        atomicAdd(sbuf + (size_t)d * 4 + 0, v.x);
        atomicAdd(sbuf + (size_t)d * 4 + 1, v.y);
        atomicAdd(sbuf + (size_t)d * 4 + 2, v.z);
        atomicAdd(sbuf + (size_t)d * 4 + 3, v.w);
    }
}

// ---------------- K4: MFMA gate MLP + attn-V fold; 1 wave = 1 node, V staged via LDS ----------------
__global__ void __launch_bounds__(256) k4_mfma(
    const int* __restrict__ rowptr, const int* __restrict__ esrc,
    const unsigned short* __restrict__ eab,
    const float* __restrict__ Weg1, const float* __restrict__ beg1,
    const float* __restrict__ Weg2, const float* __restrict__ beg2,
    const float* __restrict__ el, const float* __restrict__ sbuf,
    const unsigned short* __restrict__ Vb, float* __restrict__ agg)
{
    __shared__ __align__(16) short h_lds[4][16 * EGD];
    __shared__ __align__(16) float attn_lds[4][16][4];
    __shared__ __align__(16) unsigned short vsm[4][16 * VSTRIDE];
    const int t = threadIdx.x;
    const int wid = t >> 6, l = t & 63;
    const int q = l >> 4, c15 = l & 15;

    bf16x8 b2[8];
    #pragma unroll
    for (int tt = 0; tt < 8; ++tt) {
        #pragma unroll
        for (int j = 0; j < 8; ++j)
            b2[tt][j] = f2bf(Weg2[(q * 8 + j) * HID + tt * 16 + c15]);
    }
    bf16x8 b1f[2];
    #pragma unroll
    for (int n = 0; n < 2; ++n) {
        #pragma unroll
        for (int j = 0; j < 8; ++j)
            b1f[n][j] = (q < 2) ? f2bf(Weg1[(q * 8 + j) * EGD + n * 16 + c15]) : (short)0;
    }
    const float b1c0 = beg1[c15], b1c1 = beg1[16 + c15];
    float bg2[8];
    #pragma unroll
    for (int tt = 0; tt < 8; ++tt) bg2[tt] = beg2[tt * 16 + c15];

    const f32x4 zc = {0.f, 0.f, 0.f, 0.f};
    const int n = blockIdx.x * 4 + wid;
    const int pstart = rowptr[n], pend = rowptr[n + 1];
    const float invh = __builtin_amdgcn_rcpf(sbuf[(size_t)n * 4 + (l & 3)] + 1e-10f);
    float accv[8];
    #pragma unroll
    for (int tt = 0; tt < 8; ++tt) accv[tt] = 0.f;

    const int srow = l >> 2;
    const int ssub = l & 3;

    for (int pc = pstart; pc < pend; pc += 16) {
        const int cnt = min(16, pend - pc);
        const int sidx = (srow < cnt) ? srow : cnt - 1;
        const int srcrow = esrc[pc + sidx];
        bf16x8 vreg[4];
        #pragma unroll
        for (int i = 0; i < 4; ++i)
            vreg[i] = *(const bf16x8*)(Vb + (size_t)srcrow * HID + ssub * 32 + i * 8);
        bf16x8 a1 = {0, 0, 0, 0, 0, 0, 0, 0};
        if (q < 2) {
            if (c15 < cnt)
                a1 = *(const bf16x8*)(eab + (size_t)(pc + c15) * EDIM + q * 8);
        } else {
            const int idx2 = l & 31;
            const int slot = idx2 >> 2, head = idx2 & 3;
            float v0 = 0.f, v1 = 0.f;
            if (slot < cnt)     v0 = el[(size_t)(pc + slot) * 4 + head] * invh;
            if (slot + 8 < cnt) v1 = el[(size_t)(pc + slot + 8) * 4 + head] * invh;
            attn_lds[wid][slot][head] = v0;
            attn_lds[wid][slot + 8][head] = v1;
        }
        f32x4 c0 = __builtin_amdgcn_mfma_f32_16x16x32_bf16(a1, b1f[0], zc, 0, 0, 0);
        f32x4 c1 = __builtin_amdgcn_mfma_f32_16x16x32_bf16(a1, b1f[1], zc, 0, 0, 0);
        #pragma unroll
        for (int r = 0; r < 4; ++r) {
            h_lds[wid][(q * 4 + r) * EGD + c15]      = f2bf(gelu_f(c0[r] + b1c0));
            h_lds[wid][(q * 4 + r) * EGD + 16 + c15] = f2bf(gelu_f(c1[r] + b1c1));
        }
        #pragma unroll
        for (int i = 0; i < 4; ++i)
            *(bf16x8*)&vsm[wid][srow * VSTRIDE + ssub * 32 + i * 8] = vreg[i];
        asm volatile("s_waitcnt lgkmcnt(0)" ::: "memory");
        __builtin_amdgcn_sched_barrier(0);
        const bf16x8 a2 = *(const bf16x8*)&h_lds[wid][c15 * EGD + q * 8];
        f32x4 at[4];
        #pragma unroll
        for (int r = 0; r < 4; ++r)
            at[r] = *(const f32x4*)&attn_lds[wid][q * 4 + r][0];
        f32x4 g[8];
        #pragma unroll
        for (int tt = 0; tt < 8; ++tt)
            g[tt] = __builtin_amdgcn_mfma_f32_16x16x32_bf16(a2, b2[tt], zc, 0, 0, 0);
        #pragma unroll
        for (int tt = 0; tt < 8; ++tt) {
            #pragma unroll
            for (int r = 0; r < 4; ++r) {
                const float sg = sigmoid_fast(g[tt][r] + bg2[tt]);
                const float aw = (tt < 2) ? at[r][0] : (tt < 4) ? at[r][1]
                               : (tt < 6) ? at[r][2] : at[r][3];
                const float vv = bf2f(vsm[wid][(q * 4 + r) * VSTRIDE + tt * 16 + c15]);
                accv[tt] = fmaf(aw * sg, vv, accv[tt]);
            }
        }
    }
    #pragma unroll
    for (int tt = 0; tt < 8; ++tt) {
        accv[tt] += __shfl_xor(accv[tt], 16);
        accv[tt] += __shfl_xor(accv[tt], 32);
    }
    agg[(size_t)n * HID + (2 * q) * 16 + c15]     = accv[2 * q];
    agg[(size_t)n * HID + (2 * q + 1) * 16 + c15] = accv[2 * q + 1];
}

// ---------------- K5: Wo + FiLM + residual + LN2 + FFN + residual (16 rows / 256 thr) ----------------
__global__ void __launch_bounds__(256) k5_out(
    const float* __restrict__ agg, const unsigned short* __restrict__ Wob4,
    const float* __restrict__ bo,
    const float* __restrict__ gamma, const float* __restrict__ beta,
    const float* __restrict__ x,
    const float* __restrict__ g2, const float* __restrict__ b2,
    const unsigned short* __restrict__ Wf1b4, const float* __restrict__ bf1,
    const unsigned short* __restrict__ Wf2b4, const float* __restrict__ bf2,
    float* __restrict__ out)
{
    __shared__ float asm1[16][HID];      // agg, then xn2 (reused)
    __shared__ float xlsm[16][HID];
    __shared__ float hsm[16][2 * HID];
    const int t = threadIdx.x;
    const int base = blockIdx.x * 16;
    // stage agg
    {
        const float4* src = (const float4*)(agg + (size_t)base * HID);
        float4* dst = (float4*)asm1;
        dst[t] = src[t];
        dst[t + 256] = src[t + 256];
    }
    __syncthreads();
    const int c = t & 127, h = t >> 7, r0 = h * 8;
    // GEMM1: agg @ Wo
    float acc[8];
    #pragma unroll
    for (int r = 0; r < 8; ++r) acc[r] = 0.f;
    for (int k4 = 0; k4 < 32; ++k4) {
        const ushort4 w4 = ((const ushort4*)Wob4)[k4 * HID + c];
        const float w0 = bf2f(w4.x), w1 = bf2f(w4.y), w2 = bf2f(w4.z), w3 = bf2f(w4.w);
        #pragma unroll
        for (int r = 0; r < 8; ++r) {
            const float4 a = *(const float4*)&asm1[r0 + r][k4 * 4];
            acc[r] = fmaf(a.x, w0, acc[r]); acc[r] = fmaf(a.y, w1, acc[r]);
            acc[r] = fmaf(a.z, w2, acc[r]); acc[r] = fmaf(a.w, w3, acc[r]);
        }
    }
    // epilogue1: bias + FiLM + residual
    float xl[8];
    const float bol = bo[c];
    #pragma unroll
    for (int r = 0; r < 8; ++r) {
        const size_t idx = (size_t)(base + r0 + r) * HID + c;
        float o = acc[r] + bol;
        o = fmaf(gamma[idx], o, beta[idx]);
        xl[r] = x[idx] + o;
        xlsm[r0 + r][c] = xl[r];
    }
    __syncthreads();
    // LN2 stats + write xn2 into asm1
    {
        const int sr = t >> 4, sl = t & 15;
        float s1 = 0.f, s2 = 0.f;
        float v[8];
        #pragma unroll
        for (int j = 0; j < 8; ++j) {
            v[j] = xlsm[sr][sl + 16 * j];
            s1 += v[j]; s2 += v[j] * v[j];
        }
        #pragma unroll
        for (int m = 1; m < 16; m <<= 1) { s1 += __shfl_xor(s1, m); s2 += __shfl_xor(s2, m); }
        const float mu = s1 * (1.0f / HID);
        const float var = s2 * (1.0f / HID) - mu * mu;
        const float rstd = rsqrtf(var + 1e-5f);
        #pragma unroll
        for (int j = 0; j < 8; ++j) {
            const int col = sl + 16 * j;
            asm1[sr][col] = (v[j] - mu) * rstd * g2[col] + b2[col];
        }
    }
    __syncthreads();
    // GEMM2: xn2 @ Wf1 (N=256), col c2 = t, all 16 rows
    {
        float acc2[16];
        #pragma unroll
        for (int r = 0; r < 16; ++r) acc2[r] = 0.f;
        for (int k4 = 0; k4 < 32; ++k4) {
            const ushort4 w4 = ((const ushort4*)Wf1b4)[k4 * 256 + t];
            const float w0 = bf2f(w4.x), w1 = bf2f(w4.y), w2 = bf2f(w4.z), w3 = bf2f(w4.w);
            #pragma unroll
            for (int r = 0; r < 16; ++r) {
                const float4 a = *(const float4*)&asm1[r][k4 * 4];
                acc2[r] = fmaf(a.x, w0, acc2[r]); acc2[r] = fmaf(a.y, w1, acc2[r]);
                acc2[r] = fmaf(a.z, w2, acc2[r]); acc2[r] = fmaf(a.w, w3, acc2[r]);
            }
        }
        const float b1c = bf1[t];
        #pragma unroll
        for (int r = 0; r < 16; ++r)
            hsm[r][t] = gelu_f(acc2[r] + b1c);
    }
    __syncthreads();
    // GEMM3: hgelu @ Wf2 (K=256, N=128)
    float acc3[8];
    #pragma unroll
    for (int r = 0; r < 8; ++r) acc3[r] = 0.f;
    for (int k4 = 0; k4 < 64; ++k4) {
        const ushort4 w4 = ((const ushort4*)Wf2b4)[k4 * HID + c];
        const float w0 = bf2f(w4.x), w1 = bf2f(w4.y), w2 = bf2f(w4.z), w3 = bf2f(w4.w);
        #pragma unroll
        for (int r = 0; r < 8; ++r) {
            const float4 a = *(const float4*)&hsm[r0 + r][k4 * 4];
            acc3[r] = fmaf(a.x, w0, acc3[r]); acc3[r] = fmaf(a.y, w1, acc3[r]);
            acc3[r] = fmaf(a.z, w2, acc3[r]); acc3[r] = fmaf(a.w, w3, acc3[r]);
        }
    }
    const float bf2c = bf2[c];
    #pragma unroll
    for (int r = 0; r < 8; ++r)
        out[(size_t)(base + r0 + r) * HID + c] = xl[r] + acc3[r] + bf2c;
}

extern "C" void kernel_launch(void* const* d_in, const int* in_sizes, int n_in,
                              void* d_out, int out_size, void* d_ws, size_t ws_size,
                              hipStream_t stream) {
    const float* x     = (const float*)d_in[0];
    const int*   ei    = (const int*)d_in[1];
    const float* ea    = (const float*)d_in[2];
    const float* gamma = (const float*)d_in[3];
    const float* beta  = (const float*)d_in[4];
    const float* ln1_g = (const float*)d_in[5];
    const float* ln1_b = (const float*)d_in[6];
    const float* Wq    = (const float*)d_in[7];
    const float* Wk    = (const float*)d_in[8];
    const float* Wv    = (const float*)d_in[9];
    const float* Wo    = (const float*)d_in[10];
    const float* bo    = (const float*)d_in[11];
    const float* Wea1  = (const float*)d_in[12];
    const float* bea1  = (const float*)d_in[13];
    const float* Wea2  = (const float*)d_in[14];
    const float* bea2  = (const float*)d_in[15];
    const float* Weg1  = (const float*)d_in[16];
    const float* beg1  = (const float*)d_in[17];
    const float* Weg2  = (const float*)d_in[18];
    const float* beg2  = (const float*)d_in[19];
    const float* ln2_g = (const float*)d_in[20];
    const float* ln2_b = (const float*)d_in[21];
    const float* Wf1   = (const float*)d_in[22];
    const float* bf1   = (const float*)d_in[23];
    const float* Wf2   = (const float*)d_in[24];
    const float* bf2   = (const float*)d_in[25];

    unsigned short* Qb  = (unsigned short*)d_ws;
    unsigned short* Kb  = Qb + (size_t)N_NODES * HID;
    unsigned short* Vb  = Kb + (size_t)N_NODES * HID;
    unsigned short* eab = Vb + (size_t)N_NODES * HID;
    float* logits = (float*)(eab + (size_t)E_EDGES * EDIM);
    float* mbuf   = logits + (size_t)E_EDGES * 4;
    float* sbuf   = mbuf + (size_t)N_NODES * 4;
    int*   deg    = (int*)(sbuf + (size_t)N_NODES * 4);
    float* agg    = (float*)(deg + N_NODES);
    int*   rowptr = (int*)(agg + (size_t)N_NODES * HID);
    int*   wptr   = rowptr + (N_NODES + 1);
    int*   bsum   = wptr + N_NODES;
    int*   eidx   = bsum + 128;
    int*   esrc   = eidx + E_EDGES;
    int*   pdst   = esrc + E_EDGES;
    unsigned short* Wqb4  = (unsigned short*)(pdst + E_EDGES);
    unsigned short* Wkb4  = Wqb4 + 16384;
    unsigned short* Wvb4  = Wkb4 + 16384;
    unsigned short* Wob4  = Wvb4 + 16384;
    unsigned short* Wf1b4 = Wob4 + 16384;
    unsigned short* Wf2b4 = Wf1b4 + 32768;

    // zero mbuf, sbuf, deg
    hipMemsetAsync(mbuf, 0,
                   ((size_t)N_NODES * 4 * 2) * sizeof(float) + (size_t)N_NODES * sizeof(int),
                   stream);

    k0w_conv<<<512, 256, 0, stream>>>(Wq, Wk, Wv, Wo, Wf1, Wf2,
                                      Wqb4, Wkb4, Wvb4, Wob4, Wf1b4, Wf2b4);

    // CSR build
    k0a_degree<<<E_EDGES / 256, 256, 0, stream>>>(ei, deg);
    k0b_scan1<<<SCAN_NB, SCAN_BS, 0, stream>>>(deg, rowptr, bsum);
    k0c_scan2<<<1, 128, 0, stream>>>(bsum);
    k0d_fixup<<<SCAN_NB, SCAN_BS, 0, stream>>>(rowptr, wptr, bsum);
    k0e_scatter<<<E_EDGES / 256, 256, 0, stream>>>(ei, wptr, eidx, esrc, pdst);

    k1_ln_qkv<<<N_NODES / 16, 256, 0, stream>>>(x, ln1_g, ln1_b, Wqb4, Wkb4, Wvb4,
                                                Qb, Kb, Vb);
    k2_fused<<<(size_t)E_EDGES * 32 / 256, 256, 0, stream>>>(eidx, esrc, pdst, Qb, Kb, ea,
                                                             Wea1, bea1, Wea2, bea2,
                                                             logits, mbuf, eab);
    k3_exp_sum<<<E_EDGES / 256, 256, 0, stream>>>(pdst, mbuf, logits, sbuf);
    k4_mfma<<<N_NODES / 4, 256, 0, stream>>>(rowptr, esrc, eab,
                                             Weg1, beg1, Weg2, beg2,
                                             logits, sbuf, Vb, agg);
    k5_out<<<N_NODES / 16, 256, 0, stream>>>(agg, Wob4, bo, gamma, beta, x,
                                             ln2_g, ln2_b, Wf1b4, bf1, Wf2b4, bf2,
                                             (float*)d_out);
}

// Round 9
// 513.813 us; speedup vs baseline: 1.4384x; 1.4384x over previous
//
#include <hip/hip_runtime.h>
#include <cmath>

#define N_NODES 50000
#define E_EDGES 800000
#define HID 128
#define HEADS 4
#define EDIM 16
#define EGD 32
#define VSTRIDE 136   // ushorts per staged V row (272B)
#define SCAN_BS 512
#define SCAN_NB ((N_NODES + SCAN_BS - 1) / SCAN_BS)

typedef __attribute__((ext_vector_type(8))) short bf16x8;
typedef __attribute__((ext_vector_type(4))) float f32x4;

__device__ __forceinline__ float gelu_f(float z) {
    return 0.5f * z * (1.0f + erff(z * 0.7071067811865476f));
}
__device__ __forceinline__ float sigmoid_fast(float z) {
    return __builtin_amdgcn_rcpf(1.0f + __expf(-z));
}
__device__ __forceinline__ short f2bf(float f) {
    unsigned u = __float_as_uint(f);
    unsigned r = u + 0x7fffu + ((u >> 16) & 1u);
    return (short)(r >> 16);
}
__device__ __forceinline__ float bf2f(unsigned short u) {
    return __uint_as_float(((unsigned)u) << 16);
}
__device__ __forceinline__ ushort4 f4bf(float4 v) {
    ushort4 r;
    r.x = (unsigned short)f2bf(v.x); r.y = (unsigned short)f2bf(v.y);
    r.z = (unsigned short)f2bf(v.z); r.w = (unsigned short)f2bf(v.w);
    return r;
}

// ---------------- K0w: weights -> bf16, MFMA B-frag layout pos(k,n)=((k>>3)*N+n)*8+(k&7) ----------------
__global__ void __launch_bounds__(256) k0w_conv(
    const float* __restrict__ Wq, const float* __restrict__ Wk, const float* __restrict__ Wv,
    const float* __restrict__ Wo, const float* __restrict__ Wf1, const float* __restrict__ Wf2,
    unsigned short* __restrict__ Wqm, unsigned short* __restrict__ Wkm,
    unsigned short* __restrict__ Wvm, unsigned short* __restrict__ Wom,
    unsigned short* __restrict__ Wf1m, unsigned short* __restrict__ Wf2m)
{
    const int b = blockIdx.x, t = threadIdx.x;
    const float* src; unsigned short* dst; int idx; bool wide;
    if (b < 64)       { src = Wq;  dst = Wqm;  idx = b * 256 + t;         wide = false; }
    else if (b < 128) { src = Wk;  dst = Wkm;  idx = (b - 64) * 256 + t;  wide = false; }
    else if (b < 192) { src = Wv;  dst = Wvm;  idx = (b - 128) * 256 + t; wide = false; }
    else if (b < 256) { src = Wo;  dst = Wom;  idx = (b - 192) * 256 + t; wide = false; }
    else if (b < 384) { src = Wf1; dst = Wf1m; idx = (b - 256) * 256 + t; wide = true;  }
    else              { src = Wf2; dst = Wf2m; idx = (b - 384) * 256 + t; wide = false; }
    int k, n, N;
    if (wide) { k = idx >> 8; n = idx & 255; N = 256; }
    else      { k = idx >> 7; n = idx & 127; N = 128; }
    dst[((size_t)(k >> 3) * N + n) * 8 + (k & 7)] = (unsigned short)f2bf(src[idx]);
}

// ---------------- K1: LN1 + QKV via MFMA (16 rows / 256 threads) ----------------
// A: row=lane&15, k=(lane>>4)*8+j.  B: col=lane&15, k=(lane>>4)*8+j.  C/D: col=lane&15, row=(lane>>4)*4+reg.
__global__ void __launch_bounds__(256) k1_ln_qkv(
    const float* __restrict__ x, const float* __restrict__ g1, const float* __restrict__ b1,
    const unsigned short* __restrict__ Wqm, const unsigned short* __restrict__ Wkm,
    const unsigned short* __restrict__ Wvm,
    unsigned short* __restrict__ Qb, unsigned short* __restrict__ Kb,
    unsigned short* __restrict__ Vb)
{
    __shared__ float xsm[16][HID];
    __shared__ __align__(16) unsigned short xnb[16 * HID]; // bf16, XOR-swizzled rows
    const int t = threadIdx.x;
    const int base = blockIdx.x * 16;
    {
        const float4* src = (const float4*)(x + (size_t)base * HID);
        float4* dst = (float4*)xsm;
        dst[t] = src[t];
        dst[t + 256] = src[t + 256];
    }
    __syncthreads();
    {
        const int sr = t >> 4, sl = t & 15;
        float s1 = 0.f, s2 = 0.f, v[8];
        #pragma unroll
        for (int j = 0; j < 8; ++j) { v[j] = xsm[sr][sl + 16 * j]; s1 += v[j]; s2 += v[j] * v[j]; }
        #pragma unroll
        for (int m = 1; m < 16; m <<= 1) { s1 += __shfl_xor(s1, m); s2 += __shfl_xor(s2, m); }
        const float mu = s1 * (1.0f / HID);
        const float rstd = rsqrtf(s2 * (1.0f / HID) - mu * mu + 1e-5f);
        char* rowp = (char*)(xnb + sr * HID);
        #pragma unroll
        for (int j = 0; j < 8; ++j) {
            const int col = sl + 16 * j;
            const float nv = (v[j] - mu) * rstd * g1[col] + b1[col];
            *(unsigned short*)(rowp + ((col * 2) ^ ((sr & 7) << 4))) = (unsigned short)f2bf(nv);
        }
    }
    __syncthreads();
    const int w = t >> 6, l = t & 63, q = l >> 4, c15 = l & 15;
    bf16x8 a[4];
    {
        const char* rowp = (const char*)(xnb + c15 * HID);
        #pragma unroll
        for (int kc = 0; kc < 4; ++kc)
            a[kc] = *(const bf16x8*)(rowp + ((kc * 64 + q * 16) ^ ((c15 & 7) << 4)));
    }
    const f32x4 zc = {0.f, 0.f, 0.f, 0.f};
    #pragma unroll
    for (int ct = 0; ct < 2; ++ct) {
        const int colb = (w * 2 + ct) * 16;
        f32x4 aq = zc, ak = zc, av = zc;
        #pragma unroll
        for (int kc = 0; kc < 4; ++kc) {
            const size_t boff = (size_t)((kc * 4 + q) * HID + colb + c15) * 8;
            aq = __builtin_amdgcn_mfma_f32_16x16x32_bf16(a[kc], *(const bf16x8*)(Wqm + boff), aq, 0, 0, 0);
            ak = __builtin_amdgcn_mfma_f32_16x16x32_bf16(a[kc], *(const bf16x8*)(Wkm + boff), ak, 0, 0, 0);
            av = __builtin_amdgcn_mfma_f32_16x16x32_bf16(a[kc], *(const bf16x8*)(Wvm + boff), av, 0, 0, 0);
        }
        #pragma unroll
        for (int r = 0; r < 4; ++r) {
            const size_t idx = (size_t)(base + q * 4 + r) * HID + colb + c15;
            Qb[idx] = (unsigned short)f2bf(aq[r]);
            Kb[idx] = (unsigned short)f2bf(ak[r]);
            Vb[idx] = (unsigned short)f2bf(av[r]);
        }
    }
}

// ---------------- CSR build ----------------
__global__ void __launch_bounds__(256) k0a_degree(
    const int* __restrict__ ei, int* __restrict__ deg)
{
    const int e = blockIdx.x * 256 + threadIdx.x;
    atomicAdd(deg + ei[E_EDGES + e], 1);
}

__global__ void __launch_bounds__(SCAN_BS) k0b_scan1(
    const int* __restrict__ deg, int* __restrict__ rowptr, int* __restrict__ bsum)
{
    __shared__ int sm[SCAN_BS];
    const int t = threadIdx.x;
    const int i = blockIdx.x * SCAN_BS + t;
    const int v = (i < N_NODES) ? deg[i] : 0;
    sm[t] = v;
    __syncthreads();
    #pragma unroll
    for (int off = 1; off < SCAN_BS; off <<= 1) {
        int add = (t >= off) ? sm[t - off] : 0;
        __syncthreads();
        sm[t] += add;
        __syncthreads();
    }
    if (i < N_NODES) rowptr[i] = sm[t] - v;
    if (t == SCAN_BS - 1) bsum[blockIdx.x] = sm[t];
}

__global__ void __launch_bounds__(128) k0c_scan2(int* __restrict__ bsum)
{
    __shared__ int sm[128];
    const int t = threadIdx.x;
    const int v = (t < SCAN_NB) ? bsum[t] : 0;
    sm[t] = v;
    __syncthreads();
    #pragma unroll
    for (int off = 1; off < 128; off <<= 1) {
        int add = (t >= off) ? sm[t - off] : 0;
        __syncthreads();
        sm[t] += add;
        __syncthreads();
    }
    if (t < SCAN_NB) bsum[t] = sm[t] - v; // exclusive
}

__global__ void __launch_bounds__(SCAN_BS) k0d_fixup(
    int* __restrict__ rowptr, int* __restrict__ wptr, const int* __restrict__ bsum)
{
    const int i = blockIdx.x * SCAN_BS + threadIdx.x;
    if (i < N_NODES) {
        int r = rowptr[i] + bsum[blockIdx.x];
        rowptr[i] = r;
        wptr[i] = r;
    }
    if (i == 0) rowptr[N_NODES] = E_EDGES;
}

__global__ void __launch_bounds__(256) k0e_scatter(
    const int* __restrict__ ei, int* __restrict__ wptr,
    int* __restrict__ eidx, int* __restrict__ esrc, int* __restrict__ pdst)
{
    const int e = blockIdx.x * 256 + threadIdx.x;
    const int d = ei[E_EDGES + e];
    const int pos = atomicAdd(wptr + d, 1);
    eidx[pos] = e;
    esrc[pos] = ei[e];
    pdst[pos] = d;
}

// ---------------- K2: bf16 QK^T dot + edge-bias MLP + atomicMax + eab emit ----------------
__global__ void __launch_bounds__(256) k2_fused(
    const int* __restrict__ eidx, const int* __restrict__ esrc, const int* __restrict__ pdst,
    const unsigned short* __restrict__ Qb, const unsigned short* __restrict__ Kb,
    const float* __restrict__ ea,
    const float* __restrict__ Wea1, const float* __restrict__ bea1,
    const float* __restrict__ Wea2, const float* __restrict__ bea2,
    float* __restrict__ logits, float* __restrict__ mbuf,
    unsigned short* __restrict__ eab)
{
    const int t = threadIdx.x;
    const int p = (blockIdx.x * 256 + t) >> 5;
    const int s = t & 31;
    const int e = eidx[p];
    const int src = esrc[p];
    const int dst = pdst[p];
    const ushort4 qu = ((const ushort4*)(Qb + (size_t)dst * HID))[s];
    const ushort4 ku = ((const ushort4*)(Kb + (size_t)src * HID))[s];
    float pr = bf2f(qu.x) * bf2f(ku.x) + bf2f(qu.y) * bf2f(ku.y)
             + bf2f(qu.z) * bf2f(ku.z) + bf2f(qu.w) * bf2f(ku.w);
    pr += __shfl_xor(pr, 1);
    pr += __shfl_xor(pr, 2);
    pr += __shfl_xor(pr, 4);
    const float4* eap = (const float4*)(ea + (size_t)e * EDIM);
    float4 a0 = eap[0], a1 = eap[1], a2 = eap[2], a3 = eap[3];
    if (s < 4) {
        const float4 av = (s == 0) ? a0 : (s == 1) ? a1 : (s == 2) ? a2 : a3;
        ((ushort4*)(eab + (size_t)p * EDIM))[s] = f4bf(av);
    }
    float h = bea1[s];
    h = fmaf(a0.x, Wea1[0 * EGD + s], h);  h = fmaf(a0.y, Wea1[1 * EGD + s], h);
    h = fmaf(a0.z, Wea1[2 * EGD + s], h);  h = fmaf(a0.w, Wea1[3 * EGD + s], h);
    h = fmaf(a1.x, Wea1[4 * EGD + s], h);  h = fmaf(a1.y, Wea1[5 * EGD + s], h);
    h = fmaf(a1.z, Wea1[6 * EGD + s], h);  h = fmaf(a1.w, Wea1[7 * EGD + s], h);
    h = fmaf(a2.x, Wea1[8 * EGD + s], h);  h = fmaf(a2.y, Wea1[9 * EGD + s], h);
    h = fmaf(a2.z, Wea1[10 * EGD + s], h); h = fmaf(a2.w, Wea1[11 * EGD + s], h);
    h = fmaf(a3.x, Wea1[12 * EGD + s], h); h = fmaf(a3.y, Wea1[13 * EGD + s], h);
    h = fmaf(a3.z, Wea1[14 * EGD + s], h); h = fmaf(a3.w, Wea1[15 * EGD + s], h);
    h = gelu_f(h);
    const float4 w2 = ((const float4*)Wea2)[s];
    float b0 = h * w2.x, b1 = h * w2.y, b2 = h * w2.z, b3 = h * w2.w;
    #pragma unroll
    for (int off = 1; off < 32; off <<= 1) {
        b0 += __shfl_xor(b0, off);
        b1 += __shfl_xor(b1, off);
        b2 += __shfl_xor(b2, off);
        b3 += __shfl_xor(b3, off);
    }
    const float dv = __shfl(pr, (t & 32) + ((s & 3) << 3));
    if (s < 4) {
        const float bias = (s == 0) ? b0 : (s == 1) ? b1 : (s == 2) ? b2 : b3;
        const float lg = dv * 0.17677669529663689f + bias + bea2[s];
        logits[(size_t)p * 4 + s] = lg;
        if (lg > 0.f) atomicMax((int*)mbuf + (size_t)dst * 4 + s, __float_as_int(lg));
    }
}

// ---------------- K3: el = exp(logit - m); segmented-scan + one atomic per run ----------------
__global__ void __launch_bounds__(256) k3_exp_sum(
    const int* __restrict__ pdst, const float* __restrict__ mbuf,
    float* __restrict__ logits, float* __restrict__ sbuf)
{
    const int p = blockIdx.x * 256 + threadIdx.x;
    const int lane = threadIdx.x & 63;
    const int d = pdst[p];
    float4 lg = *(const float4*)(logits + (size_t)p * 4);
    const float4 mv = *(const float4*)(mbuf + (size_t)d * 4);
    lg.x = __expf(lg.x - mv.x);
    lg.y = __expf(lg.y - mv.y);
    lg.z = __expf(lg.z - mv.z);
    lg.w = __expf(lg.w - mv.w);
    *(float4*)(logits + (size_t)p * 4) = lg;
    float4 v = lg;
    #pragma unroll
    for (int off = 1; off < 64; off <<= 1) {
        const int du = __shfl_up(d, off);
        const float ux = __shfl_up(v.x, off);
        const float uy = __shfl_up(v.y, off);
        const float uz = __shfl_up(v.z, off);
        const float uw = __shfl_up(v.w, off);
        if (lane >= off && du == d) { v.x += ux; v.y += uy; v.z += uz; v.w += uw; }
    }
    const int dn = __shfl_down(d, 1);
    if (lane == 63 || dn != d) {
        atomicAdd(sbuf + (size_t)d * 4 + 0, v.x);
        atomicAdd(sbuf + (size_t)d * 4 + 1, v.y);
        atomicAdd(sbuf + (size_t)d * 4 + 2, v.z);
        atomicAdd(sbuf + (size_t)d * 4 + 3, v.w);
    }
}

// ---------------- K4: MFMA gate MLP + attn-V fold; 1 wave = 1 node; writes bf16 agg ----------------
__global__ void __launch_bounds__(256) k4_mfma(
    const int* __restrict__ rowptr, const int* __restrict__ esrc,
    const unsigned short* __restrict__ eab,
    const float* __restrict__ Weg1, const float* __restrict__ beg1,
    const float* __restrict__ Weg2, const float* __restrict__ beg2,
    const float* __restrict__ el, const float* __restrict__ sbuf,
    const unsigned short* __restrict__ Vb, unsigned short* __restrict__ aggb)
{
    __shared__ __align__(16) short h_lds[4][16 * EGD];
    __shared__ __align__(16) float attn_lds[4][16][4];
    __shared__ __align__(16) unsigned short vsm[4][16 * VSTRIDE];
    const int t = threadIdx.x;
    const int wid = t >> 6, l = t & 63;
    const int q = l >> 4, c15 = l & 15;

    bf16x8 b2[8];
    #pragma unroll
    for (int tt = 0; tt < 8; ++tt) {
        #pragma unroll
        for (int j = 0; j < 8; ++j)
            b2[tt][j] = f2bf(Weg2[(q * 8 + j) * HID + tt * 16 + c15]);
    }
    bf16x8 b1f[2];
    #pragma unroll
    for (int n = 0; n < 2; ++n) {
        #pragma unroll
        for (int j = 0; j < 8; ++j)
            b1f[n][j] = (q < 2) ? f2bf(Weg1[(q * 8 + j) * EGD + n * 16 + c15]) : (short)0;
    }
    const float b1c0 = beg1[c15], b1c1 = beg1[16 + c15];
    float bg2[8];
    #pragma unroll
    for (int tt = 0; tt < 8; ++tt) bg2[tt] = beg2[tt * 16 + c15];

    const f32x4 zc = {0.f, 0.f, 0.f, 0.f};
    const int n = blockIdx.x * 4 + wid;
    const int pstart = rowptr[n], pend = rowptr[n + 1];
    const float invh = __builtin_amdgcn_rcpf(sbuf[(size_t)n * 4 + (l & 3)] + 1e-10f);
    float accv[8];
    #pragma unroll
    for (int tt = 0; tt < 8; ++tt) accv[tt] = 0.f;

    const int srow = l >> 2;
    const int ssub = l & 3;

    for (int pc = pstart; pc < pend; pc += 16) {
        const int cnt = min(16, pend - pc);
        const int sidx = (srow < cnt) ? srow : cnt - 1;
        const int srcrow = esrc[pc + sidx];
        bf16x8 vreg[4];
        #pragma unroll
        for (int i = 0; i < 4; ++i)
            vreg[i] = *(const bf16x8*)(Vb + (size_t)srcrow * HID + ssub * 32 + i * 8);
        bf16x8 a1 = {0, 0, 0, 0, 0, 0, 0, 0};
        if (q < 2) {
            if (c15 < cnt)
                a1 = *(const bf16x8*)(eab + (size_t)(pc + c15) * EDIM + q * 8);
        } else {
            const int idx2 = l & 31;
            const int slot = idx2 >> 2, head = idx2 & 3;
            float v0 = 0.f, v1 = 0.f;
            if (slot < cnt)     v0 = el[(size_t)(pc + slot) * 4 + head] * invh;
            if (slot + 8 < cnt) v1 = el[(size_t)(pc + slot + 8) * 4 + head] * invh;
            attn_lds[wid][slot][head] = v0;
            attn_lds[wid][slot + 8][head] = v1;
        }
        f32x4 c0 = __builtin_amdgcn_mfma_f32_16x16x32_bf16(a1, b1f[0], zc, 0, 0, 0);
        f32x4 c1 = __builtin_amdgcn_mfma_f32_16x16x32_bf16(a1, b1f[1], zc, 0, 0, 0);
        #pragma unroll
        for (int r = 0; r < 4; ++r) {
            h_lds[wid][(q * 4 + r) * EGD + c15]      = f2bf(gelu_f(c0[r] + b1c0));
            h_lds[wid][(q * 4 + r) * EGD + 16 + c15] = f2bf(gelu_f(c1[r] + b1c1));
        }
        #pragma unroll
        for (int i = 0; i < 4; ++i)
            *(bf16x8*)&vsm[wid][srow * VSTRIDE + ssub * 32 + i * 8] = vreg[i];
        asm volatile("s_waitcnt lgkmcnt(0)" ::: "memory");
        __builtin_amdgcn_sched_barrier(0);
        const bf16x8 a2 = *(const bf16x8*)&h_lds[wid][c15 * EGD + q * 8];
        f32x4 at[4];
        #pragma unroll
        for (int r = 0; r < 4; ++r)
            at[r] = *(const f32x4*)&attn_lds[wid][q * 4 + r][0];
        f32x4 g[8];
        #pragma unroll
        for (int tt = 0; tt < 8; ++tt)
            g[tt] = __builtin_amdgcn_mfma_f32_16x16x32_bf16(a2, b2[tt], zc, 0, 0, 0);
        #pragma unroll
        for (int tt = 0; tt < 8; ++tt) {
            #pragma unroll
            for (int r = 0; r < 4; ++r) {
                const float sg = sigmoid_fast(g[tt][r] + bg2[tt]);
                const float aw = (tt < 2) ? at[r][0] : (tt < 4) ? at[r][1]
                               : (tt < 6) ? at[r][2] : at[r][3];
                const float vv = bf2f(vsm[wid][(q * 4 + r) * VSTRIDE + tt * 16 + c15]);
                accv[tt] = fmaf(aw * sg, vv, accv[tt]);
            }
        }
    }
    #pragma unroll
    for (int tt = 0; tt < 8; ++tt) {
        accv[tt] += __shfl_xor(accv[tt], 16);
        accv[tt] += __shfl_xor(accv[tt], 32);
    }
    aggb[(size_t)n * HID + (2 * q) * 16 + c15]     = (unsigned short)f2bf(accv[2 * q]);
    aggb[(size_t)n * HID + (2 * q + 1) * 16 + c15] = (unsigned short)f2bf(accv[2 * q + 1]);
}

// ---------------- K5: Wo + FiLM + residual + LN2 + FFN + residual, via MFMA ----------------
__global__ void __launch_bounds__(256) k5_out(
    const unsigned short* __restrict__ aggb, const unsigned short* __restrict__ Wom,
    const float* __restrict__ bo,
    const float* __restrict__ gamma, const float* __restrict__ beta,
    const float* __restrict__ x,
    const float* __restrict__ g2, const float* __restrict__ b2,
    const unsigned short* __restrict__ Wf1m, const float* __restrict__ bf1,
    const unsigned short* __restrict__ Wf2m, const float* __restrict__ bf2,
    float* __restrict__ out)
{
    __shared__ float xlsm[16][HID];
    __shared__ __align__(16) unsigned short xnb[16 * HID];      // bf16 LN2 out, swizzled
    __shared__ __align__(16) unsigned short hb[16 * 2 * HID];   // bf16 gelu out, swizzled
    const int t = threadIdx.x;
    const int base = blockIdx.x * 16;
    const int w = t >> 6, l = t & 63, q = l >> 4, c15 = l & 15;
    const f32x4 zc = {0.f, 0.f, 0.f, 0.f};

    // GEMM1: A-frags streamed from global bf16 agg
    bf16x8 a[4];
    #pragma unroll
    for (int kc = 0; kc < 4; ++kc)
        a[kc] = *(const bf16x8*)(aggb + (size_t)(base + c15) * HID + kc * 32 + q * 8);
    float xl[2][4];
    #pragma unroll
    for (int ct = 0; ct < 2; ++ct) {
        const int colb = (w * 2 + ct) * 16;
        f32x4 acc = zc;
        #pragma unroll
        for (int kc = 0; kc < 4; ++kc)
            acc = __builtin_amdgcn_mfma_f32_16x16x32_bf16(
                a[kc], *(const bf16x8*)(Wom + (size_t)((kc * 4 + q) * HID + colb + c15) * 8), acc, 0, 0, 0);
        const float bov = bo[colb + c15];
        #pragma unroll
        for (int r = 0; r < 4; ++r) {
            const int row = q * 4 + r;
            const size_t idx = (size_t)(base + row) * HID + colb + c15;
            float o = acc[r] + bov;
            o = fmaf(gamma[idx], o, beta[idx]);
            const float v = x[idx] + o;
            xl[ct][r] = v;
            xlsm[row][colb + c15] = v;
        }
    }
    __syncthreads();
    // LN2 -> xnb (bf16 swizzled)
    {
        const int sr = t >> 4, sl = t & 15;
        float s1 = 0.f, s2 = 0.f, v[8];
        #pragma unroll
        for (int j = 0; j < 8; ++j) { v[j] = xlsm[sr][sl + 16 * j]; s1 += v[j]; s2 += v[j] * v[j]; }
        #pragma unroll
        for (int m = 1; m < 16; m <<= 1) { s1 += __shfl_xor(s1, m); s2 += __shfl_xor(s2, m); }
        const float mu = s1 * (1.0f / HID);
        const float rstd = rsqrtf(s2 * (1.0f / HID) - mu * mu + 1e-5f);
        char* rowp = (char*)(xnb + sr * HID);
        #pragma unroll
        for (int j = 0; j < 8; ++j) {
            const int col = sl + 16 * j;
            const float nv = (v[j] - mu) * rstd * g2[col] + b2[col];
            *(unsigned short*)(rowp + ((col * 2) ^ ((sr & 7) << 4))) = (unsigned short)f2bf(nv);
        }
    }
    __syncthreads();
    // GEMM2: xn2 @ Wf1 (N=256) -> gelu -> hb
    {
        const char* rowp = (const char*)(xnb + c15 * HID);
        bf16x8 a2[4];
        #pragma unroll
        for (int kc = 0; kc < 4; ++kc)
            a2[kc] = *(const bf16x8*)(rowp + ((kc * 64 + q * 16) ^ ((c15 & 7) << 4)));
        #pragma unroll
        for (int ct = 0; ct < 4; ++ct) {
            const int colb = (w * 4 + ct) * 16;
            f32x4 acc = zc;
            #pragma unroll
            for (int kc = 0; kc < 4; ++kc)
                acc = __builtin_amdgcn_mfma_f32_16x16x32_bf16(
                    a2[kc], *(const bf16x8*)(Wf1m + (size_t)((kc * 4 + q) * 256 + colb + c15) * 8), acc, 0, 0, 0);
            const float b1v = bf1[colb + c15];
            #pragma unroll
            for (int r = 0; r < 4; ++r) {
                const int row = q * 4 + r;
                const float hg = gelu_f(acc[r] + b1v);
                *(unsigned short*)((char*)(hb + row * 2 * HID)
                    + (((colb + c15) * 2) ^ ((row & 7) << 4))) = (unsigned short)f2bf(hg);
            }
        }
    }
    __syncthreads();
    // GEMM3: hgelu @ Wf2 (K=256) + residual
    {
        const char* rowp = (const char*)(hb + c15 * 2 * HID);
        bf16x8 a3[8];
        #pragma unroll
        for (int kc = 0; kc < 8; ++kc)
            a3[kc] = *(const bf16x8*)(rowp + ((kc * 64 + q * 16) ^ ((c15 & 7) << 4)));
        #pragma unroll
        for (int ct = 0; ct < 2; ++ct) {
            const int colb = (w * 2 + ct) * 16;
            f32x4 acc = zc;
            #pragma unroll
            for (int kc = 0; kc < 8; ++kc)
                acc = __builtin_amdgcn_mfma_f32_16x16x32_bf16(
                    a3[kc], *(const bf16x8*)(Wf2m + (size_t)((kc * 4 + q) * HID + colb + c15) * 8), acc, 0, 0, 0);
            const float b2v = bf2[colb + c15];
            #pragma unroll
            for (int r = 0; r < 4; ++r) {
                const int row = q * 4 + r;
                out[(size_t)(base + row) * HID + colb + c15] = xl[ct][r] + acc[r] + b2v;
            }
        }
    }
}

extern "C" void kernel_launch(void* const* d_in, const int* in_sizes, int n_in,
                              void* d_out, int out_size, void* d_ws, size_t ws_size,
                              hipStream_t stream) {
    const float* x     = (const float*)d_in[0];
    const int*   ei    = (const int*)d_in[1];
    const float* ea    = (const float*)d_in[2];
    const float* gamma = (const float*)d_in[3];
    const float* beta  = (const float*)d_in[4];
    const float* ln1_g = (const float*)d_in[5];
    const float* ln1_b = (const float*)d_in[6];
    const float* Wq    = (const float*)d_in[7];
    const float* Wk    = (const float*)d_in[8];
    const float* Wv    = (const float*)d_in[9];
    const float* Wo    = (const float*)d_in[10];
    const float* bo    = (const float*)d_in[11];
    const float* Wea1  = (const float*)d_in[12];
    const float* bea1  = (const float*)d_in[13];
    const float* Wea2  = (const float*)d_in[14];
    const float* bea2  = (const float*)d_in[15];
    const float* Weg1  = (const float*)d_in[16];
    const float* beg1  = (const float*)d_in[17];
    const float* Weg2  = (const float*)d_in[18];
    const float* beg2  = (const float*)d_in[19];
    const float* ln2_g = (const float*)d_in[20];
    const float* ln2_b = (const float*)d_in[21];
    const float* Wf1   = (const float*)d_in[22];
    const float* bf1   = (const float*)d_in[23];
    const float* Wf2   = (const float*)d_in[24];
    const float* bf2   = (const float*)d_in[25];

    unsigned short* Qb   = (unsigned short*)d_ws;
    unsigned short* Kb   = Qb + (size_t)N_NODES * HID;
    unsigned short* Vb   = Kb + (size_t)N_NODES * HID;
    unsigned short* aggb = Vb + (size_t)N_NODES * HID;
    unsigned short* eab  = aggb + (size_t)N_NODES * HID;
    unsigned short* Wqm  = eab + (size_t)E_EDGES * EDIM;
    unsigned short* Wkm  = Wqm + 16384;
    unsigned short* Wvm  = Wkm + 16384;
    unsigned short* Wom  = Wvm + 16384;
    unsigned short* Wf1m = Wom + 16384;
    unsigned short* Wf2m = Wf1m + 32768;
    float* logits = (float*)(Wf2m + 32768);
    float* mbuf   = logits + (size_t)E_EDGES * 4;
    float* sbuf   = mbuf + (size_t)N_NODES * 4;
    int*   deg    = (int*)(sbuf + (size_t)N_NODES * 4);
    int*   rowptr = deg + N_NODES;
    int*   wptr   = rowptr + (N_NODES + 1);
    int*   bsum   = wptr + N_NODES;
    int*   eidx   = bsum + 128;
    int*   esrc   = eidx + E_EDGES;
    int*   pdst   = esrc + E_EDGES;

    // zero mbuf, sbuf, deg (contiguous)
    hipMemsetAsync(mbuf, 0,
                   ((size_t)N_NODES * 4 * 2) * sizeof(float) + (size_t)N_NODES * sizeof(int),
                   stream);

    k0w_conv<<<512, 256, 0, stream>>>(Wq, Wk, Wv, Wo, Wf1, Wf2,
                                      Wqm, Wkm, Wvm, Wom, Wf1m, Wf2m);

    // CSR build
    k0a_degree<<<E_EDGES / 256, 256, 0, stream>>>(ei, deg);
    k0b_scan1<<<SCAN_NB, SCAN_BS, 0, stream>>>(deg, rowptr, bsum);
    k0c_scan2<<<1, 128, 0, stream>>>(bsum);
    k0d_fixup<<<SCAN_NB, SCAN_BS, 0, stream>>>(rowptr, wptr, bsum);
    k0e_scatter<<<E_EDGES / 256, 256, 0, stream>>>(ei, wptr, eidx, esrc, pdst);

    k1_ln_qkv<<<N_NODES / 16, 256, 0, stream>>>(x, ln1_g, ln1_b, Wqm, Wkm, Wvm,
                                                Qb, Kb, Vb);
    k2_fused<<<(size_t)E_EDGES * 32 / 256, 256, 0, stream>>>(eidx, esrc, pdst, Qb, Kb, ea,
                                                             Wea1, bea1, Wea2, bea2,
                                                             logits, mbuf, eab);
    k3_exp_sum<<<E_EDGES / 256, 256, 0, stream>>>(pdst, mbuf, logits, sbuf);
    k4_mfma<<<N_NODES / 4, 256, 0, stream>>>(rowptr, esrc, eab,
                                             Weg1, beg1, Weg2, beg2,
                                             logits, sbuf, Vb, aggb);
    k5_out<<<N_NODES / 16, 256, 0, stream>>>(aggb, Wom, bo, gamma, beta, x,
                                             ln2_g, ln2_b, Wf1m, bf1, Wf2m, bf2,
                                             (float*)d_out);
}

// Round 10
// 425.319 us; speedup vs baseline: 1.7376x; 1.2081x over previous
//
#include <hip/hip_runtime.h>
#include <cmath>

#define N_NODES 50000
#define E_EDGES 800000
#define HID 128
#define HEADS 4
#define EDIM 16
#define EGD 32
#define VSTRIDE 136   // ushorts per staged V row (272B)
#define SCAN_BS 512
#define SCAN_NB ((N_NODES + SCAN_BS - 1) / SCAN_BS)

typedef __attribute__((ext_vector_type(8))) short bf16x8;
typedef __attribute__((ext_vector_type(4))) float f32x4;

__device__ __forceinline__ float gelu_f(float z) {
    return 0.5f * z * (1.0f + erff(z * 0.7071067811865476f));
}
__device__ __forceinline__ float sigmoid_fast(float z) {
    return __builtin_amdgcn_rcpf(1.0f + __expf(-z));
}
__device__ __forceinline__ short f2bf(float f) {
    unsigned u = __float_as_uint(f);
    unsigned r = u + 0x7fffu + ((u >> 16) & 1u);
    return (short)(r >> 16);
}
__device__ __forceinline__ float bf2f(unsigned short u) {
    return __uint_as_float(((unsigned)u) << 16);
}

// ---------------- K0w: weights -> bf16, MFMA B-frag layout pos(k,n)=((k>>3)*N+n)*8+(k&7) ----------------
__global__ void __launch_bounds__(256) k0w_conv(
    const float* __restrict__ Wq, const float* __restrict__ Wk, const float* __restrict__ Wv,
    const float* __restrict__ Wo, const float* __restrict__ Wf1, const float* __restrict__ Wf2,
    const float* __restrict__ Wea1, const float* __restrict__ Wea2,
    unsigned short* __restrict__ Wqm, unsigned short* __restrict__ Wkm,
    unsigned short* __restrict__ Wvm, unsigned short* __restrict__ Wom,
    unsigned short* __restrict__ Wf1m, unsigned short* __restrict__ Wf2m,
    unsigned short* __restrict__ Wea1m, unsigned short* __restrict__ Wea2m)
{
    const int b = blockIdx.x, t = threadIdx.x;
    if (b == 512) {
        // Wea1m: K padded 16->32, N=32 -> 1024 entries
        for (int i = t; i < 1024; i += 256) {
            const int j = i & 7, rest = i >> 3;
            const int n = rest & 31, q = rest >> 5, k = q * 8 + j;
            Wea1m[i] = (unsigned short)((k < EDIM) ? f2bf(Wea1[k * EGD + n]) : (short)0);
        }
        // Wea2m: K=32, N padded 4->16 -> 512 entries
        for (int i = t; i < 512; i += 256) {
            const int j = i & 7, rest = i >> 3;
            const int n = rest & 15, q = rest >> 4, k = q * 8 + j;
            Wea2m[i] = (unsigned short)((n < HEADS) ? f2bf(Wea2[k * HEADS + n]) : (short)0);
        }
        return;
    }
    const float* src; unsigned short* dst; int idx; bool wide;
    if (b < 64)       { src = Wq;  dst = Wqm;  idx = b * 256 + t;         wide = false; }
    else if (b < 128) { src = Wk;  dst = Wkm;  idx = (b - 64) * 256 + t;  wide = false; }
    else if (b < 192) { src = Wv;  dst = Wvm;  idx = (b - 128) * 256 + t; wide = false; }
    else if (b < 256) { src = Wo;  dst = Wom;  idx = (b - 192) * 256 + t; wide = false; }
    else if (b < 384) { src = Wf1; dst = Wf1m; idx = (b - 256) * 256 + t; wide = true;  }
    else              { src = Wf2; dst = Wf2m; idx = (b - 384) * 256 + t; wide = false; }
    int k, n, N;
    if (wide) { k = idx >> 8; n = idx & 255; N = 256; }
    else      { k = idx >> 7; n = idx & 127; N = 128; }
    dst[((size_t)(k >> 3) * N + n) * 8 + (k & 7)] = (unsigned short)f2bf(src[idx]);
}

// ---------------- K1: LN1 + QKV via MFMA (16 rows / 256 threads) ----------------
// A: row=lane&15, k=(lane>>4)*8+j.  B: col=lane&15, k=(lane>>4)*8+j.  C/D: col=lane&15, row=(lane>>4)*4+reg.
__global__ void __launch_bounds__(256) k1_ln_qkv(
    const float* __restrict__ x, const float* __restrict__ g1, const float* __restrict__ b1,
    const unsigned short* __restrict__ Wqm, const unsigned short* __restrict__ Wkm,
    const unsigned short* __restrict__ Wvm,
    unsigned short* __restrict__ Qb, unsigned short* __restrict__ Kb,
    unsigned short* __restrict__ Vb)
{
    __shared__ float xsm[16][HID];
    __shared__ __align__(16) unsigned short xnb[16 * HID]; // bf16, XOR-swizzled rows
    const int t = threadIdx.x;
    const int base = blockIdx.x * 16;
    {
        const float4* src = (const float4*)(x + (size_t)base * HID);
        float4* dst = (float4*)xsm;
        dst[t] = src[t];
        dst[t + 256] = src[t + 256];
    }
    __syncthreads();
    {
        const int sr = t >> 4, sl = t & 15;
        float s1 = 0.f, s2 = 0.f, v[8];
        #pragma unroll
        for (int j = 0; j < 8; ++j) { v[j] = xsm[sr][sl + 16 * j]; s1 += v[j]; s2 += v[j] * v[j]; }
        #pragma unroll
        for (int m = 1; m < 16; m <<= 1) { s1 += __shfl_xor(s1, m); s2 += __shfl_xor(s2, m); }
        const float mu = s1 * (1.0f / HID);
        const float rstd = rsqrtf(s2 * (1.0f / HID) - mu * mu + 1e-5f);
        char* rowp = (char*)(xnb + sr * HID);
        #pragma unroll
        for (int j = 0; j < 8; ++j) {
            const int col = sl + 16 * j;
            const float nv = (v[j] - mu) * rstd * g1[col] + b1[col];
            *(unsigned short*)(rowp + ((col * 2) ^ ((sr & 7) << 4))) = (unsigned short)f2bf(nv);
        }
    }
    __syncthreads();
    const int w = t >> 6, l = t & 63, q = l >> 4, c15 = l & 15;
    bf16x8 a[4];
    {
        const char* rowp = (const char*)(xnb + c15 * HID);
        #pragma unroll
        for (int kc = 0; kc < 4; ++kc)
            a[kc] = *(const bf16x8*)(rowp + ((kc * 64 + q * 16) ^ ((c15 & 7) << 4)));
    }
    const f32x4 zc = {0.f, 0.f, 0.f, 0.f};
    #pragma unroll
    for (int ct = 0; ct < 2; ++ct) {
        const int colb = (w * 2 + ct) * 16;
        f32x4 aq = zc, ak = zc, av = zc;
        #pragma unroll
        for (int kc = 0; kc < 4; ++kc) {
            const size_t boff = (size_t)((kc * 4 + q) * HID + colb + c15) * 8;
            aq = __builtin_amdgcn_mfma_f32_16x16x32_bf16(a[kc], *(const bf16x8*)(Wqm + boff), aq, 0, 0, 0);
            ak = __builtin_amdgcn_mfma_f32_16x16x32_bf16(a[kc], *(const bf16x8*)(Wkm + boff), ak, 0, 0, 0);
            av = __builtin_amdgcn_mfma_f32_16x16x32_bf16(a[kc], *(const bf16x8*)(Wvm + boff), av, 0, 0, 0);
        }
        #pragma unroll
        for (int r = 0; r < 4; ++r) {
            const size_t idx = (size_t)(base + q * 4 + r) * HID + colb + c15;
            Qb[idx] = (unsigned short)f2bf(aq[r]);
            Kb[idx] = (unsigned short)f2bf(ak[r]);
            Vb[idx] = (unsigned short)f2bf(av[r]);
        }
    }
}

// ---------------- CSR build ----------------
__global__ void __launch_bounds__(256) k0a_degree(
    const int* __restrict__ ei, int* __restrict__ deg)
{
    const int e = blockIdx.x * 256 + threadIdx.x;
    atomicAdd(deg + ei[E_EDGES + e], 1);
}

__global__ void __launch_bounds__(SCAN_BS) k0b_scan1(
    const int* __restrict__ deg, int* __restrict__ rowptr, int* __restrict__ bsum)
{
    __shared__ int sm[SCAN_BS];
    const int t = threadIdx.x;
    const int i = blockIdx.x * SCAN_BS + t;
    const int v = (i < N_NODES) ? deg[i] : 0;
    sm[t] = v;
    __syncthreads();
    #pragma unroll
    for (int off = 1; off < SCAN_BS; off <<= 1) {
        int add = (t >= off) ? sm[t - off] : 0;
        __syncthreads();
        sm[t] += add;
        __syncthreads();
    }
    if (i < N_NODES) rowptr[i] = sm[t] - v;
    if (t == SCAN_BS - 1) bsum[blockIdx.x] = sm[t];
}

__global__ void __launch_bounds__(128) k0c_scan2(int* __restrict__ bsum)
{
    __shared__ int sm[128];
    const int t = threadIdx.x;
    const int v = (t < SCAN_NB) ? bsum[t] : 0;
    sm[t] = v;
    __syncthreads();
    #pragma unroll
    for (int off = 1; off < 128; off <<= 1) {
        int add = (t >= off) ? sm[t - off] : 0;
        __syncthreads();
        sm[t] += add;
        __syncthreads();
    }
    if (t < SCAN_NB) bsum[t] = sm[t] - v; // exclusive
}

__global__ void __launch_bounds__(SCAN_BS) k0d_fixup(
    int* __restrict__ rowptr, int* __restrict__ wptr, const int* __restrict__ bsum)
{
    const int i = blockIdx.x * SCAN_BS + threadIdx.x;
    if (i < N_NODES) {
        int r = rowptr[i] + bsum[blockIdx.x];
        rowptr[i] = r;
        wptr[i] = r;
    }
    if (i == 0) rowptr[N_NODES] = E_EDGES;
}

__global__ void __launch_bounds__(256) k0e_scatter(
    const int* __restrict__ ei, int* __restrict__ wptr,
    int* __restrict__ eidx, int* __restrict__ esrc, int* __restrict__ pdst)
{
    const int e = blockIdx.x * 256 + threadIdx.x;
    const int d = ei[E_EDGES + e];
    const int pos = atomicAdd(wptr + d, 1);
    eidx[pos] = e;
    esrc[pos] = ei[e];
    pdst[pos] = d;
}

// ---------------- K2: QK dots (16 lanes/edge) + bias MLP via MFMA (16 edges/wave) ----------------
__global__ void __launch_bounds__(256) k2_fused(
    const int* __restrict__ eidx, const int* __restrict__ esrc, const int* __restrict__ pdst,
    const unsigned short* __restrict__ Qb, const unsigned short* __restrict__ Kb,
    const float* __restrict__ ea,
    const unsigned short* __restrict__ Wea1m, const float* __restrict__ bea1,
    const unsigned short* __restrict__ Wea2m, const float* __restrict__ bea2,
    float* __restrict__ logits, float* __restrict__ mbuf,
    unsigned short* __restrict__ eab)
{
    __shared__ __align__(16) float dot_lds[4][16][4];   // per wave [edge][head]
    __shared__ __align__(16) short h_lds[4][16 * EGD];  // per wave [edge][hidden] bf16
    const int t = threadIdx.x;
    const int w = t >> 6, l = t & 63;
    const int p0 = blockIdx.x * 64 + w * 16;            // this wave's 16 CSR slots

    // ---- phase A: QK dots, 4 chunks x 4 edges, 16 lanes/edge ----
    {
        const int er = l >> 4;       // edge within chunk
        const int i = l & 15;
        const int head = i >> 2, part = i & 3;
        #pragma unroll
        for (int cc = 0; cc < 4; ++cc) {
            const int p = p0 + cc * 4 + er;
            const int dst = pdst[p], src = esrc[p];
            const bf16x8 qv = *(const bf16x8*)(Qb + (size_t)dst * HID + head * 32 + part * 8);
            const bf16x8 kv = *(const bf16x8*)(Kb + (size_t)src * HID + head * 32 + part * 8);
            float s = 0.f;
            #pragma unroll
            for (int j = 0; j < 8; ++j)
                s = fmaf(bf2f((unsigned short)qv[j]), bf2f((unsigned short)kv[j]), s);
            s += __shfl_xor(s, 1);
            s += __shfl_xor(s, 2);
            if (part == 0) dot_lds[w][cc * 4 + er][head] = s * 0.17677669529663689f;
        }
    }

    // ---- phase B: bias MLP via MFMA over this wave's 16 edges ----
    const int q = l >> 4, c15 = l & 15;
    bf16x8 a1 = {0, 0, 0, 0, 0, 0, 0, 0};
    if (q < 2) {
        const int e = eidx[p0 + c15];
        const float4 u0 = *(const float4*)(ea + (size_t)e * EDIM + q * 8);
        const float4 u1 = *(const float4*)(ea + (size_t)e * EDIM + q * 8 + 4);
        a1[0] = f2bf(u0.x); a1[1] = f2bf(u0.y); a1[2] = f2bf(u0.z); a1[3] = f2bf(u0.w);
        a1[4] = f2bf(u1.x); a1[5] = f2bf(u1.y); a1[6] = f2bf(u1.z); a1[7] = f2bf(u1.w);
        *(bf16x8*)(eab + (size_t)(p0 + c15) * EDIM + q * 8) = a1;  // emit p-order bf16 ea
    }
    const bf16x8 b1f0 = *(const bf16x8*)(Wea1m + (size_t)(q * 32 + c15) * 8);
    const bf16x8 b1f1 = *(const bf16x8*)(Wea1m + (size_t)(q * 32 + 16 + c15) * 8);
    const f32x4 zc = {0.f, 0.f, 0.f, 0.f};
    f32x4 c0 = __builtin_amdgcn_mfma_f32_16x16x32_bf16(a1, b1f0, zc, 0, 0, 0);
    f32x4 c1 = __builtin_amdgcn_mfma_f32_16x16x32_bf16(a1, b1f1, zc, 0, 0, 0);
    const float bb0 = bea1[c15], bb1 = bea1[16 + c15];
    #pragma unroll
    for (int r = 0; r < 4; ++r) {
        h_lds[w][(q * 4 + r) * EGD + c15]      = f2bf(gelu_f(c0[r] + bb0));
        h_lds[w][(q * 4 + r) * EGD + 16 + c15] = f2bf(gelu_f(c1[r] + bb1));
    }
    asm volatile("s_waitcnt lgkmcnt(0)" ::: "memory");
    __builtin_amdgcn_sched_barrier(0);
    const bf16x8 a2 = *(const bf16x8*)&h_lds[w][c15 * EGD + q * 8];
    const bf16x8 b2 = *(const bf16x8*)(Wea2m + (size_t)(q * 16 + c15) * 8);
    f32x4 d2 = __builtin_amdgcn_mfma_f32_16x16x32_bf16(a2, b2, zc, 0, 0, 0);
    // D2: lane(q,c15) holds bias[edge=q*4+r][head=c15]; c15<4 valid
    if (c15 < 4) {
        const float be = bea2[c15];
        #pragma unroll
        for (int r = 0; r < 4; ++r) {
            const int edge = q * 4 + r;
            const int p = p0 + edge;
            const float lg = dot_lds[w][edge][c15] + d2[r] + be;
            logits[(size_t)p * 4 + c15] = lg;
            if (lg > 0.f) {
                const int dst = pdst[p];
                atomicMax((int*)mbuf + (size_t)dst * 4 + c15, __float_as_int(lg));
            }
        }
    }
}

// ---------------- K3: el = exp(logit - m); segmented-scan + one atomic per run ----------------
__global__ void __launch_bounds__(256) k3_exp_sum(
    const int* __restrict__ pdst, const float* __restrict__ mbuf,
    float* __restrict__ logits, float* __restrict__ sbuf)
{
    const int p = blockIdx.x * 256 + threadIdx.x;
    const int lane = threadIdx.x & 63;
    const int d = pdst[p];
    float4 lg = *(const float4*)(logits + (size_t)p * 4);
    const float4 mv = *(const float4*)(mbuf + (size_t)d * 4);
    lg.x = __expf(lg.x - mv.x);
    lg.y = __expf(lg.y - mv.y);
    lg.z = __expf(lg.z - mv.z);
    lg.w = __expf(lg.w - mv.w);
    *(float4*)(logits + (size_t)p * 4) = lg;
    float4 v = lg;
    #pragma unroll
    for (int off = 1; off < 64; off <<= 1) {
        const int du = __shfl_up(d, off);
        const float ux = __shfl_up(v.x, off);
        const float uy = __shfl_up(v.y, off);
        const float uz = __shfl_up(v.z, off);
        const float uw = __shfl_up(v.w, off);
        if (lane >= off && du == d) { v.x += ux; v.y += uy; v.z += uz; v.w += uw; }
    }
    const int dn = __shfl_down(d, 1);
    if (lane == 63 || dn != d) {
        atomicAdd(sbuf + (size_t)d * 4 + 0, v.x);
        atomicAdd(sbuf + (size_t)d * 4 + 1, v.y);
        atomicAdd(sbuf + (size_t)d * 4 + 2, v.z);
        atomicAdd(sbuf + (size_t)d * 4 + 3, v.w);
    }
}

// ---------------- K4: MFMA gate MLP + attn-V fold; 1 wave = 1 node; writes bf16 agg ----------------
__global__ void __launch_bounds__(256) k4_mfma(
    const int* __restrict__ rowptr, const int* __restrict__ esrc,
    const unsigned short* __restrict__ eab,
    const float* __restrict__ Weg1, const float* __restrict__ beg1,
    const float* __restrict__ Weg2, const float* __restrict__ beg2,
    const float* __restrict__ el, const float* __restrict__ sbuf,
    const unsigned short* __restrict__ Vb, unsigned short* __restrict__ aggb)
{
    __shared__ __align__(16) short h_lds[4][16 * EGD];
    __shared__ __align__(16) float attn_lds[4][16][4];
    __shared__ __align__(16) unsigned short vsm[4][16 * VSTRIDE];
    const int t = threadIdx.x;
    const int wid = t >> 6, l = t & 63;
    const int q = l >> 4, c15 = l & 15;

    bf16x8 b2[8];
    #pragma unroll
    for (int tt = 0; tt < 8; ++tt) {
        #pragma unroll
        for (int j = 0; j < 8; ++j)
            b2[tt][j] = f2bf(Weg2[(q * 8 + j) * HID + tt * 16 + c15]);
    }
    bf16x8 b1f[2];
    #pragma unroll
    for (int n = 0; n < 2; ++n) {
        #pragma unroll
        for (int j = 0; j < 8; ++j)
            b1f[n][j] = (q < 2) ? f2bf(Weg1[(q * 8 + j) * EGD + n * 16 + c15]) : (short)0;
    }
    const float b1c0 = beg1[c15], b1c1 = beg1[16 + c15];
    float bg2[8];
    #pragma unroll
    for (int tt = 0; tt < 8; ++tt) bg2[tt] = beg2[tt * 16 + c15];

    const f32x4 zc = {0.f, 0.f, 0.f, 0.f};
    const int n = blockIdx.x * 4 + wid;
    const int pstart = rowptr[n], pend = rowptr[n + 1];
    const float invh = __builtin_amdgcn_rcpf(sbuf[(size_t)n * 4 + (l & 3)] + 1e-10f);
    float accv[8];
    #pragma unroll
    for (int tt = 0; tt < 8; ++tt) accv[tt] = 0.f;

    const int srow = l >> 2;
    const int ssub = l & 3;

    for (int pc = pstart; pc < pend; pc += 16) {
        const int cnt = min(16, pend - pc);
        const int sidx = (srow < cnt) ? srow : cnt - 1;
        const int srcrow = esrc[pc + sidx];
        bf16x8 vreg[4];
        #pragma unroll
        for (int i = 0; i < 4; ++i)
            vreg[i] = *(const bf16x8*)(Vb + (size_t)srcrow * HID + ssub * 32 + i * 8);
        bf16x8 a1 = {0, 0, 0, 0, 0, 0, 0, 0};
        if (q < 2) {
            if (c15 < cnt)
                a1 = *(const bf16x8*)(eab + (size_t)(pc + c15) * EDIM + q * 8);
        } else {
            const int idx2 = l & 31;
            const int slot = idx2 >> 2, head = idx2 & 3;
            float v0 = 0.f, v1 = 0.f;
            if (slot < cnt)     v0 = el[(size_t)(pc + slot) * 4 + head] * invh;
            if (slot + 8 < cnt) v1 = el[(size_t)(pc + slot + 8) * 4 + head] * invh;
            attn_lds[wid][slot][head] = v0;
            attn_lds[wid][slot + 8][head] = v1;
        }
        f32x4 c0 = __builtin_amdgcn_mfma_f32_16x16x32_bf16(a1, b1f[0], zc, 0, 0, 0);
        f32x4 c1 = __builtin_amdgcn_mfma_f32_16x16x32_bf16(a1, b1f[1], zc, 0, 0, 0);
        #pragma unroll
        for (int r = 0; r < 4; ++r) {
            h_lds[wid][(q * 4 + r) * EGD + c15]      = f2bf(gelu_f(c0[r] + b1c0));
            h_lds[wid][(q * 4 + r) * EGD + 16 + c15] = f2bf(gelu_f(c1[r] + b1c1));
        }
        #pragma unroll
        for (int i = 0; i < 4; ++i)
            *(bf16x8*)&vsm[wid][srow * VSTRIDE + ssub * 32 + i * 8] = vreg[i];
        asm volatile("s_waitcnt lgkmcnt(0)" ::: "memory");
        __builtin_amdgcn_sched_barrier(0);
        const bf16x8 a2 = *(const bf16x8*)&h_lds[wid][c15 * EGD + q * 8];
        f32x4 at[4];
        #pragma unroll
        for (int r = 0; r < 4; ++r)
            at[r] = *(const f32x4*)&attn_lds[wid][q * 4 + r][0];
        f32x4 g[8];
        #pragma unroll
        for (int tt = 0; tt < 8; ++tt)
            g[tt] = __builtin_amdgcn_mfma_f32_16x16x32_bf16(a2, b2[tt], zc, 0, 0, 0);
        #pragma unroll
        for (int tt = 0; tt < 8; ++tt) {
            #pragma unroll
            for (int r = 0; r < 4; ++r) {
                const float sg = sigmoid_fast(g[tt][r] + bg2[tt]);
                const float aw = (tt < 2) ? at[r][0] : (tt < 4) ? at[r][1]
                               : (tt < 6) ? at[r][2] : at[r][3];
                const float vv = bf2f(vsm[wid][(q * 4 + r) * VSTRIDE + tt * 16 + c15]);
                accv[tt] = fmaf(aw * sg, vv, accv[tt]);
            }
        }
    }
    #pragma unroll
    for (int tt = 0; tt < 8; ++tt) {
        accv[tt] += __shfl_xor(accv[tt], 16);
        accv[tt] += __shfl_xor(accv[tt], 32);
    }
    aggb[(size_t)n * HID + (2 * q) * 16 + c15]     = (unsigned short)f2bf(accv[2 * q]);
    aggb[(size_t)n * HID + (2 * q + 1) * 16 + c15] = (unsigned short)f2bf(accv[2 * q + 1]);
}

// ---------------- K5: Wo + FiLM + residual + LN2 + FFN + residual, via MFMA ----------------
__global__ void __launch_bounds__(256) k5_out(
    const unsigned short* __restrict__ aggb, const unsigned short* __restrict__ Wom,
    const float* __restrict__ bo,
    const float* __restrict__ gamma, const float* __restrict__ beta,
    const float* __restrict__ x,
    const float* __restrict__ g2, const float* __restrict__ b2,
    const unsigned short* __restrict__ Wf1m, const float* __restrict__ bf1,
    const unsigned short* __restrict__ Wf2m, const float* __restrict__ bf2,
    float* __restrict__ out)
{
    __shared__ float xlsm[16][HID];
    __shared__ __align__(16) unsigned short xnb[16 * HID];
    __shared__ __align__(16) unsigned short hb[16 * 2 * HID];
    const int t = threadIdx.x;
    const int base = blockIdx.x * 16;
    const int w = t >> 6, l = t & 63, q = l >> 4, c15 = l & 15;
    const f32x4 zc = {0.f, 0.f, 0.f, 0.f};

    bf16x8 a[4];
    #pragma unroll
    for (int kc = 0; kc < 4; ++kc)
        a[kc] = *(const bf16x8*)(aggb + (size_t)(base + c15) * HID + kc * 32 + q * 8);
    float xl[2][4];
    #pragma unroll
    for (int ct = 0; ct < 2; ++ct) {
        const int colb = (w * 2 + ct) * 16;
        f32x4 acc = zc;
        #pragma unroll
        for (int kc = 0; kc < 4; ++kc)
            acc = __builtin_amdgcn_mfma_f32_16x16x32_bf16(
                a[kc], *(const bf16x8*)(Wom + (size_t)((kc * 4 + q) * HID + colb + c15) * 8), acc, 0, 0, 0);
        const float bov = bo[colb + c15];
        #pragma unroll
        for (int r = 0; r < 4; ++r) {
            const int row = q * 4 + r;
            const size_t idx = (size_t)(base + row) * HID + colb + c15;
            float o = acc[r] + bov;
            o = fmaf(gamma[idx], o, beta[idx]);
            const float v = x[idx] + o;
            xl[ct][r] = v;
            xlsm[row][colb + c15] = v;
        }
    }
    __syncthreads();
    {
        const int sr = t >> 4, sl = t & 15;
        float s1 = 0.f, s2 = 0.f, v[8];
        #pragma unroll
        for (int j = 0; j < 8; ++j) { v[j] = xlsm[sr][sl + 16 * j]; s1 += v[j]; s2 += v[j] * v[j]; }
        #pragma unroll
        for (int m = 1; m < 16; m <<= 1) { s1 += __shfl_xor(s1, m); s2 += __shfl_xor(s2, m); }
        const float mu = s1 * (1.0f / HID);
        const float rstd = rsqrtf(s2 * (1.0f / HID) - mu * mu + 1e-5f);
        char* rowp = (char*)(xnb + sr * HID);
        #pragma unroll
        for (int j = 0; j < 8; ++j) {
            const int col = sl + 16 * j;
            const float nv = (v[j] - mu) * rstd * g2[col] + b2[col];
            *(unsigned short*)(rowp + ((col * 2) ^ ((sr & 7) << 4))) = (unsigned short)f2bf(nv);
        }
    }
    __syncthreads();
    {
        const char* rowp = (const char*)(xnb + c15 * HID);
        bf16x8 a2[4];
        #pragma unroll
        for (int kc = 0; kc < 4; ++kc)
            a2[kc] = *(const bf16x8*)(rowp + ((kc * 64 + q * 16) ^ ((c15 & 7) << 4)));
        #pragma unroll
        for (int ct = 0; ct < 4; ++ct) {
            const int colb = (w * 4 + ct) * 16;
            f32x4 acc = zc;
            #pragma unroll
            for (int kc = 0; kc < 4; ++kc)
                acc = __builtin_amdgcn_mfma_f32_16x16x32_bf16(
                    a2[kc], *(const bf16x8*)(Wf1m + (size_t)((kc * 4 + q) * 256 + colb + c15) * 8), acc, 0, 0, 0);
            const float b1v = bf1[colb + c15];
            #pragma unroll
            for (int r = 0; r < 4; ++r) {
                const int row = q * 4 + r;
                const float hg = gelu_f(acc[r] + b1v);
                *(unsigned short*)((char*)(hb + row * 2 * HID)
                    + (((colb + c15) * 2) ^ ((row & 7) << 4))) = (unsigned short)f2bf(hg);
            }
        }
    }
    __syncthreads();
    {
        const char* rowp = (const char*)(hb + c15 * 2 * HID);
        bf16x8 a3[8];
        #pragma unroll
        for (int kc = 0; kc < 8; ++kc)
            a3[kc] = *(const bf16x8*)(rowp + ((kc * 64 + q * 16) ^ ((c15 & 7) << 4)));
        #pragma unroll
        for (int ct = 0; ct < 2; ++ct) {
            const int colb = (w * 2 + ct) * 16;
            f32x4 acc = zc;
            #pragma unroll
            for (int kc = 0; kc < 8; ++kc)
                acc = __builtin_amdgcn_mfma_f32_16x16x32_bf16(
                    a3[kc], *(const bf16x8*)(Wf2m + (size_t)((kc * 4 + q) * HID + colb + c15) * 8), acc, 0, 0, 0);
            const float b2v = bf2[colb + c15];
            #pragma unroll
            for (int r = 0; r < 4; ++r) {
                const int row = q * 4 + r;
                out[(size_t)(base + row) * HID + colb + c15] = xl[ct][r] + acc[r] + b2v;
            }
        }
    }
}

extern "C" void kernel_launch(void* const* d_in, const int* in_sizes, int n_in,
                              void* d_out, int out_size, void* d_ws, size_t ws_size,
                              hipStream_t stream) {
    const float* x     = (const float*)d_in[0];
    const int*   ei    = (const int*)d_in[1];
    const float* ea    = (const float*)d_in[2];
    const float* gamma = (const float*)d_in[3];
    const float* beta  = (const float*)d_in[4];
    const float* ln1_g = (const float*)d_in[5];
    const float* ln1_b = (const float*)d_in[6];
    const float* Wq    = (const float*)d_in[7];
    const float* Wk    = (const float*)d_in[8];
    const float* Wv    = (const float*)d_in[9];
    const float* Wo    = (const float*)d_in[10];
    const float* bo    = (const float*)d_in[11];
    const float* Wea1  = (const float*)d_in[12];
    const float* bea1  = (const float*)d_in[13];
    const float* Wea2  = (const float*)d_in[14];
    const float* bea2  = (const float*)d_in[15];
    const float* Weg1  = (const float*)d_in[16];
    const float* beg1  = (const float*)d_in[17];
    const float* Weg2  = (const float*)d_in[18];
    const float* beg2  = (const float*)d_in[19];
    const float* ln2_g = (const float*)d_in[20];
    const float* ln2_b = (const float*)d_in[21];
    const float* Wf1   = (const float*)d_in[22];
    const float* bf1   = (const float*)d_in[23];
    const float* Wf2   = (const float*)d_in[24];
    const float* bf2   = (const float*)d_in[25];

    unsigned short* Qb   = (unsigned short*)d_ws;
    unsigned short* Kb   = Qb + (size_t)N_NODES * HID;
    unsigned short* Vb   = Kb + (size_t)N_NODES * HID;
    unsigned short* aggb = Vb + (size_t)N_NODES * HID;
    unsigned short* eab  = aggb + (size_t)N_NODES * HID;
    unsigned short* Wqm  = eab + (size_t)E_EDGES * EDIM;
    unsigned short* Wkm  = Wqm + 16384;
    unsigned short* Wvm  = Wkm + 16384;
    unsigned short* Wom  = Wvm + 16384;
    unsigned short* Wf1m = Wom + 16384;
    unsigned short* Wf2m = Wf1m + 32768;
    unsigned short* Wea1m = Wf2m + 32768;
    unsigned short* Wea2m = Wea1m + 1024;
    float* logits = (float*)(Wea2m + 512);
    float* mbuf   = logits + (size_t)E_EDGES * 4;
    float* sbuf   = mbuf + (size_t)N_NODES * 4;
    int*   deg    = (int*)(sbuf + (size_t)N_NODES * 4);
    int*   rowptr = deg + N_NODES;
    int*   wptr   = rowptr + (N_NODES + 1);
    int*   bsum   = wptr + N_NODES;
    int*   eidx   = bsum + 128;
    int*   esrc   = eidx + E_EDGES;
    int*   pdst   = esrc + E_EDGES;

    // zero mbuf, sbuf, deg (contiguous)
    hipMemsetAsync(mbuf, 0,
                   ((size_t)N_NODES * 4 * 2) * sizeof(float) + (size_t)N_NODES * sizeof(int),
                   stream);

    k0w_conv<<<513, 256, 0, stream>>>(Wq, Wk, Wv, Wo, Wf1, Wf2, Wea1, Wea2,
                                      Wqm, Wkm, Wvm, Wom, Wf1m, Wf2m, Wea1m, Wea2m);

    // CSR build
    k0a_degree<<<E_EDGES / 256, 256, 0, stream>>>(ei, deg);
    k0b_scan1<<<SCAN_NB, SCAN_BS, 0, stream>>>(deg, rowptr, bsum);
    k0c_scan2<<<1, 128, 0, stream>>>(bsum);
    k0d_fixup<<<SCAN_NB, SCAN_BS, 0, stream>>>(rowptr, wptr, bsum);
    k0e_scatter<<<E_EDGES / 256, 256, 0, stream>>>(ei, wptr, eidx, esrc, pdst);

    k1_ln_qkv<<<N_NODES / 16, 256, 0, stream>>>(x, ln1_g, ln1_b, Wqm, Wkm, Wvm,
                                                Qb, Kb, Vb);
    k2_fused<<<E_EDGES / 64, 256, 0, stream>>>(eidx, esrc, pdst, Qb, Kb, ea,
                                               Wea1m, bea1, Wea2m, bea2,
                                               logits, mbuf, eab);
    k3_exp_sum<<<E_EDGES / 256, 256, 0, stream>>>(pdst, mbuf, logits, sbuf);
    k4_mfma<<<N_NODES / 4, 256, 0, stream>>>(rowptr, esrc, eab,
                                             Weg1, beg1, Weg2, beg2,
                                             logits, sbuf, Vb, aggb);
    k5_out<<<N_NODES / 16, 256, 0, stream>>>(aggb, Wom, bo, gamma, beta, x,
                                             ln2_g, ln2_b, Wf1m, bf1, Wf2m, bf2,
                                             (float*)d_out);
}

// Round 11
// 392.817 us; speedup vs baseline: 1.8814x; 1.0827x over previous
//
#include <hip/hip_runtime.h>
#include <cmath>

#define N_NODES 50000
#define E_EDGES 800000
#define HID 128
#define HEADS 4
#define EDIM 16
#define EGD 32
#define VSTRIDE 136   // ushorts per staged V row (272B, 16B-aligned rows)
#define SCAN_BS 512
#define SCAN_NB ((N_NODES + SCAN_BS - 1) / SCAN_BS)

typedef __attribute__((ext_vector_type(8))) short bf16x8;
typedef __attribute__((ext_vector_type(4))) float f32x4;

__device__ __forceinline__ float gelu_f(float z) {
    return 0.5f * z * (1.0f + erff(z * 0.7071067811865476f));
}
__device__ __forceinline__ float sigmoid_fast(float z) {
    return __builtin_amdgcn_rcpf(1.0f + __expf(-z));
}
__device__ __forceinline__ short f2bf(float f) {
    unsigned u = __float_as_uint(f);
    unsigned r = u + 0x7fffu + ((u >> 16) & 1u);
    return (short)(r >> 16);
}
__device__ __forceinline__ float bf2f(unsigned short u) {
    return __uint_as_float(((unsigned)u) << 16);
}

// ---------------- K0w: weights -> bf16, MFMA B-frag layout pos(k,n)=((k>>3)*N+n)*8+(k&7) ----------------
__global__ void __launch_bounds__(256) k0w_conv(
    const float* __restrict__ Wq, const float* __restrict__ Wk, const float* __restrict__ Wv,
    const float* __restrict__ Wo, const float* __restrict__ Wf1, const float* __restrict__ Wf2,
    const float* __restrict__ Wea1, const float* __restrict__ Wea2,
    unsigned short* __restrict__ Wqm, unsigned short* __restrict__ Wkm,
    unsigned short* __restrict__ Wvm, unsigned short* __restrict__ Wom,
    unsigned short* __restrict__ Wf1m, unsigned short* __restrict__ Wf2m,
    unsigned short* __restrict__ Wea1m, unsigned short* __restrict__ Wea2m)
{
    const int b = blockIdx.x, t = threadIdx.x;
    if (b == 512) {
        for (int i = t; i < 1024; i += 256) {
            const int j = i & 7, rest = i >> 3;
            const int n = rest & 31, q = rest >> 5, k = q * 8 + j;
            Wea1m[i] = (unsigned short)((k < EDIM) ? f2bf(Wea1[k * EGD + n]) : (short)0);
        }
        for (int i = t; i < 512; i += 256) {
            const int j = i & 7, rest = i >> 3;
            const int n = rest & 15, q = rest >> 4, k = q * 8 + j;
            Wea2m[i] = (unsigned short)((n < HEADS) ? f2bf(Wea2[k * HEADS + n]) : (short)0);
        }
        return;
    }
    const float* src; unsigned short* dst; int idx; bool wide;
    if (b < 64)       { src = Wq;  dst = Wqm;  idx = b * 256 + t;         wide = false; }
    else if (b < 128) { src = Wk;  dst = Wkm;  idx = (b - 64) * 256 + t;  wide = false; }
    else if (b < 192) { src = Wv;  dst = Wvm;  idx = (b - 128) * 256 + t; wide = false; }
    else if (b < 256) { src = Wo;  dst = Wom;  idx = (b - 192) * 256 + t; wide = false; }
    else if (b < 384) { src = Wf1; dst = Wf1m; idx = (b - 256) * 256 + t; wide = true;  }
    else              { src = Wf2; dst = Wf2m; idx = (b - 384) * 256 + t; wide = false; }
    int k, n, N;
    if (wide) { k = idx >> 8; n = idx & 255; N = 256; }
    else      { k = idx >> 7; n = idx & 127; N = 128; }
    dst[((size_t)(k >> 3) * N + n) * 8 + (k & 7)] = (unsigned short)f2bf(src[idx]);
}

// ---------------- K1: LN1 + QKV via MFMA (16 rows / 256 threads) ----------------
// A: row=lane&15, k=(lane>>4)*8+j.  B: col=lane&15, k=(lane>>4)*8+j.  C/D: col=lane&15, row=(lane>>4)*4+reg.
__global__ void __launch_bounds__(256) k1_ln_qkv(
    const float* __restrict__ x, const float* __restrict__ g1, const float* __restrict__ b1,
    const unsigned short* __restrict__ Wqm, const unsigned short* __restrict__ Wkm,
    const unsigned short* __restrict__ Wvm,
    unsigned short* __restrict__ Qb, unsigned short* __restrict__ Kb,
    unsigned short* __restrict__ Vb)
{
    __shared__ float xsm[16][HID];
    __shared__ __align__(16) unsigned short xnb[16 * HID]; // bf16, XOR-swizzled rows
    const int t = threadIdx.x;
    const int base = blockIdx.x * 16;
    {
        const float4* src = (const float4*)(x + (size_t)base * HID);
        float4* dst = (float4*)xsm;
        dst[t] = src[t];
        dst[t + 256] = src[t + 256];
    }
    __syncthreads();
    {
        const int sr = t >> 4, sl = t & 15;
        float s1 = 0.f, s2 = 0.f, v[8];
        #pragma unroll
        for (int j = 0; j < 8; ++j) { v[j] = xsm[sr][sl + 16 * j]; s1 += v[j]; s2 += v[j] * v[j]; }
        #pragma unroll
        for (int m = 1; m < 16; m <<= 1) { s1 += __shfl_xor(s1, m); s2 += __shfl_xor(s2, m); }
        const float mu = s1 * (1.0f / HID);
        const float rstd = rsqrtf(s2 * (1.0f / HID) - mu * mu + 1e-5f);
        char* rowp = (char*)(xnb + sr * HID);
        #pragma unroll
        for (int j = 0; j < 8; ++j) {
            const int col = sl + 16 * j;
            const float nv = (v[j] - mu) * rstd * g1[col] + b1[col];
            *(unsigned short*)(rowp + ((col * 2) ^ ((sr & 7) << 4))) = (unsigned short)f2bf(nv);
        }
    }
    __syncthreads();
    const int w = t >> 6, l = t & 63, q = l >> 4, c15 = l & 15;
    bf16x8 a[4];
    {
        const char* rowp = (const char*)(xnb + c15 * HID);
        #pragma unroll
        for (int kc = 0; kc < 4; ++kc)
            a[kc] = *(const bf16x8*)(rowp + ((kc * 64 + q * 16) ^ ((c15 & 7) << 4)));
    }
    const f32x4 zc = {0.f, 0.f, 0.f, 0.f};
    #pragma unroll
    for (int ct = 0; ct < 2; ++ct) {
        const int colb = (w * 2 + ct) * 16;
        f32x4 aq = zc, ak = zc, av = zc;
        #pragma unroll
        for (int kc = 0; kc < 4; ++kc) {
            const size_t boff = (size_t)((kc * 4 + q) * HID + colb + c15) * 8;
            aq = __builtin_amdgcn_mfma_f32_16x16x32_bf16(a[kc], *(const bf16x8*)(Wqm + boff), aq, 0, 0, 0);
            ak = __builtin_amdgcn_mfma_f32_16x16x32_bf16(a[kc], *(const bf16x8*)(Wkm + boff), ak, 0, 0, 0);
            av = __builtin_amdgcn_mfma_f32_16x16x32_bf16(a[kc], *(const bf16x8*)(Wvm + boff), av, 0, 0, 0);
        }
        #pragma unroll
        for (int r = 0; r < 4; ++r) {
            const size_t idx = (size_t)(base + q * 4 + r) * HID + colb + c15;
            Qb[idx] = (unsigned short)f2bf(aq[r]);
            Kb[idx] = (unsigned short)f2bf(ak[r]);
            Vb[idx] = (unsigned short)f2bf(av[r]);
        }
    }
}

// ---------------- CSR build ----------------
__global__ void __launch_bounds__(256) k0a_degree(
    const int* __restrict__ ei, int* __restrict__ deg)
{
    const int e = blockIdx.x * 256 + threadIdx.x;
    atomicAdd(deg + ei[E_EDGES + e], 1);
}

__global__ void __launch_bounds__(SCAN_BS) k0b_scan1(
    const int* __restrict__ deg, int* __restrict__ rowptr, int* __restrict__ bsum)
{
    __shared__ int sm[SCAN_BS];
    const int t = threadIdx.x;
    const int i = blockIdx.x * SCAN_BS + t;
    const int v = (i < N_NODES) ? deg[i] : 0;
    sm[t] = v;
    __syncthreads();
    #pragma unroll
    for (int off = 1; off < SCAN_BS; off <<= 1) {
        int add = (t >= off) ? sm[t - off] : 0;
        __syncthreads();
        sm[t] += add;
        __syncthreads();
    }
    if (i < N_NODES) rowptr[i] = sm[t] - v;
    if (t == SCAN_BS - 1) bsum[blockIdx.x] = sm[t];
}

__global__ void __launch_bounds__(128) k0c_scan2(int* __restrict__ bsum)
{
    __shared__ int sm[128];
    const int t = threadIdx.x;
    const int v = (t < SCAN_NB) ? bsum[t] : 0;
    sm[t] = v;
    __syncthreads();
    #pragma unroll
    for (int off = 1; off < 128; off <<= 1) {
        int add = (t >= off) ? sm[t - off] : 0;
        __syncthreads();
        sm[t] += add;
        __syncthreads();
    }
    if (t < SCAN_NB) bsum[t] = sm[t] - v; // exclusive
}

__global__ void __launch_bounds__(SCAN_BS) k0d_fixup(
    int* __restrict__ rowptr, int* __restrict__ wptr, const int* __restrict__ bsum)
{
    const int i = blockIdx.x * SCAN_BS + threadIdx.x;
    if (i < N_NODES) {
        int r = rowptr[i] + bsum[blockIdx.x];
        rowptr[i] = r;
        wptr[i] = r;
    }
    if (i == 0) rowptr[N_NODES] = E_EDGES;
}

__global__ void __launch_bounds__(256) k0e_scatter(
    const int* __restrict__ ei, int* __restrict__ wptr,
    int* __restrict__ eidx, int* __restrict__ esrc, int* __restrict__ pdst)
{
    const int e = blockIdx.x * 256 + threadIdx.x;
    const int d = ei[E_EDGES + e];
    const int pos = atomicAdd(wptr + d, 1);
    eidx[pos] = e;
    esrc[pos] = ei[e];
    pdst[pos] = d;
}

// ---------------- K2: QK dots (16 lanes/edge) + bias MLP via MFMA (16 edges/wave) ----------------
__global__ void __launch_bounds__(256) k2_fused(
    const int* __restrict__ eidx, const int* __restrict__ esrc, const int* __restrict__ pdst,
    const unsigned short* __restrict__ Qb, const unsigned short* __restrict__ Kb,
    const float* __restrict__ ea,
    const unsigned short* __restrict__ Wea1m, const float* __restrict__ bea1,
    const unsigned short* __restrict__ Wea2m, const float* __restrict__ bea2,
    float* __restrict__ logits, float* __restrict__ mbuf,
    unsigned short* __restrict__ eab)
{
    __shared__ __align__(16) float dot_lds[4][16][4];   // per wave [edge][head]
    __shared__ __align__(16) short h_lds[4][16 * EGD];  // per wave [edge][hidden] bf16
    const int t = threadIdx.x;
    const int w = t >> 6, l = t & 63;
    const int p0 = blockIdx.x * 64 + w * 16;            // this wave's 16 CSR slots

    // ---- phase A: QK dots, 4 chunks x 4 edges, 16 lanes/edge ----
    {
        const int er = l >> 4;
        const int i = l & 15;
        const int head = i >> 2, part = i & 3;
        #pragma unroll
        for (int cc = 0; cc < 4; ++cc) {
            const int p = p0 + cc * 4 + er;
            const int dst = pdst[p], src = esrc[p];
            const bf16x8 qv = *(const bf16x8*)(Qb + (size_t)dst * HID + head * 32 + part * 8);
            const bf16x8 kv = *(const bf16x8*)(Kb + (size_t)src * HID + head * 32 + part * 8);
            float s = 0.f;
            #pragma unroll
            for (int j = 0; j < 8; ++j)
                s = fmaf(bf2f((unsigned short)qv[j]), bf2f((unsigned short)kv[j]), s);
            s += __shfl_xor(s, 1);
            s += __shfl_xor(s, 2);
            if (part == 0) dot_lds[w][cc * 4 + er][head] = s * 0.17677669529663689f;
        }
    }

    // ---- phase B: bias MLP via MFMA over this wave's 16 edges ----
    const int q = l >> 4, c15 = l & 15;
    bf16x8 a1 = {0, 0, 0, 0, 0, 0, 0, 0};
    if (q < 2) {
        const int e = eidx[p0 + c15];
        const float4 u0 = *(const float4*)(ea + (size_t)e * EDIM + q * 8);
        const float4 u1 = *(const float4*)(ea + (size_t)e * EDIM + q * 8 + 4);
        a1[0] = f2bf(u0.x); a1[1] = f2bf(u0.y); a1[2] = f2bf(u0.z); a1[3] = f2bf(u0.w);
        a1[4] = f2bf(u1.x); a1[5] = f2bf(u1.y); a1[6] = f2bf(u1.z); a1[7] = f2bf(u1.w);
        *(bf16x8*)(eab + (size_t)(p0 + c15) * EDIM + q * 8) = a1;  // emit p-order bf16 ea
    }
    const bf16x8 b1f0 = *(const bf16x8*)(Wea1m + (size_t)(q * 32 + c15) * 8);
    const bf16x8 b1f1 = *(const bf16x8*)(Wea1m + (size_t)(q * 32 + 16 + c15) * 8);
    const f32x4 zc = {0.f, 0.f, 0.f, 0.f};
    f32x4 c0 = __builtin_amdgcn_mfma_f32_16x16x32_bf16(a1, b1f0, zc, 0, 0, 0);
    f32x4 c1 = __builtin_amdgcn_mfma_f32_16x16x32_bf16(a1, b1f1, zc, 0, 0, 0);
    const float bb0 = bea1[c15], bb1 = bea1[16 + c15];
    #pragma unroll
    for (int r = 0; r < 4; ++r) {
        h_lds[w][(q * 4 + r) * EGD + c15]      = f2bf(gelu_f(c0[r] + bb0));
        h_lds[w][(q * 4 + r) * EGD + 16 + c15] = f2bf(gelu_f(c1[r] + bb1));
    }
    asm volatile("s_waitcnt lgkmcnt(0)" ::: "memory");
    __builtin_amdgcn_sched_barrier(0);
    const bf16x8 a2 = *(const bf16x8*)&h_lds[w][c15 * EGD + q * 8];
    const bf16x8 b2 = *(const bf16x8*)(Wea2m + (size_t)(q * 16 + c15) * 8);
    f32x4 d2 = __builtin_amdgcn_mfma_f32_16x16x32_bf16(a2, b2, zc, 0, 0, 0);
    if (c15 < 4) {
        const float be = bea2[c15];
        #pragma unroll
        for (int r = 0; r < 4; ++r) {
            const int edge = q * 4 + r;
            const int p = p0 + edge;
            const float lg = dot_lds[w][edge][c15] + d2[r] + be;
            logits[(size_t)p * 4 + c15] = lg;
            if (lg > 0.f) {
                const int dst = pdst[p];
                atomicMax((int*)mbuf + (size_t)dst * 4 + c15, __float_as_int(lg));
            }
        }
    }
}

// ---------------- K4: softmax + MFMA gate MLP + attn-V fold; 1 wave = 1 node ----------------
__global__ void __launch_bounds__(256) k4_mfma(
    const int* __restrict__ rowptr, const int* __restrict__ esrc,
    const unsigned short* __restrict__ eab,
    const float* __restrict__ Weg1, const float* __restrict__ beg1,
    const float* __restrict__ Weg2, const float* __restrict__ beg2,
    const float* __restrict__ logits, const float* __restrict__ mbuf,
    const unsigned short* __restrict__ Vb, unsigned short* __restrict__ aggb)
{
    __shared__ __align__(16) short h_lds[4][16 * EGD];
    __shared__ __align__(16) float attn_lds[4][16][4];
    __shared__ __align__(16) unsigned short vsm[4][16 * VSTRIDE];
    const int t = threadIdx.x;
    const int wid = t >> 6, l = t & 63;
    const int q = l >> 4, c15 = l & 15;

    bf16x8 b2[8];
    #pragma unroll
    for (int tt = 0; tt < 8; ++tt) {
        #pragma unroll
        for (int j = 0; j < 8; ++j)
            b2[tt][j] = f2bf(Weg2[(q * 8 + j) * HID + tt * 16 + c15]);
    }
    bf16x8 b1f[2];
    #pragma unroll
    for (int n = 0; n < 2; ++n) {
        #pragma unroll
        for (int j = 0; j < 8; ++j)
            b1f[n][j] = (q < 2) ? f2bf(Weg1[(q * 8 + j) * EGD + n * 16 + c15]) : (short)0;
    }
    const float b1c0 = beg1[c15], b1c1 = beg1[16 + c15];
    float bg2[8];
    #pragma unroll
    for (int tt = 0; tt < 8; ++tt) bg2[tt] = beg2[tt * 16 + c15];

    const f32x4 zc = {0.f, 0.f, 0.f, 0.f};
    const int n = blockIdx.x * 4 + wid;
    const int pstart = rowptr[n], pend = rowptr[n + 1];

    // esrc preload: lane l holds edge pstart+l (covers deg<=64; fallback below)
    const int pidx = pstart + l;
    const int my_src = (pidx < pend) ? esrc[pidx] : 0;

    // ---- pass 1: softmax denominator (fused k3) ----
    const int slot = l >> 2, head = l & 3;
    const float m_l = mbuf[(size_t)n * 4 + head];
    float ssum = 0.f, el0 = 0.f;
    for (int pc = pstart; pc < pend; pc += 16) {
        const int cnt = min(16, pend - pc);
        float el = 0.f;
        if (slot < cnt) el = __expf(logits[(size_t)(pc + slot) * 4 + head] - m_l);
        if (pc == pstart) el0 = el;
        ssum += el;
    }
    ssum += __shfl_xor(ssum, 4);
    ssum += __shfl_xor(ssum, 8);
    ssum += __shfl_xor(ssum, 16);
    ssum += __shfl_xor(ssum, 32);
    const float invh = __builtin_amdgcn_rcpf(ssum + 1e-10f);

    float accv[8];
    #pragma unroll
    for (int tt = 0; tt < 8; ++tt) accv[tt] = 0.f;

    const int srow = l >> 2;
    const int ssub = l & 3;

    for (int pc = pstart; pc < pend; pc += 16) {
        const int cnt = min(16, pend - pc);
        // ---- V staging: srcrow via shfl of preloaded esrc (no global load in chain) ----
        const int sidx = (srow < cnt) ? srow : cnt - 1;
        const int rel = pc - pstart + sidx;
        const int srcrow = (rel < 64) ? __shfl(my_src, rel) : esrc[pc + sidx];
        bf16x8 vreg[4];
        #pragma unroll
        for (int i = 0; i < 4; ++i)
            vreg[i] = *(const bf16x8*)(Vb + (size_t)srcrow * HID + ssub * 32 + i * 8);
        // ---- attn staging: all 64 lanes, one value each ----
        const float el = (pc == pstart) ? el0
            : ((slot < cnt) ? __expf(logits[(size_t)(pc + slot) * 4 + head] - m_l) : 0.f);
        attn_lds[wid][slot][head] = el * invh;
        // ---- a1 (lanes q<2) ----
        bf16x8 a1 = {0, 0, 0, 0, 0, 0, 0, 0};
        if (q < 2 && c15 < cnt)
            a1 = *(const bf16x8*)(eab + (size_t)(pc + c15) * EDIM + q * 8);
        // ---- layer-1 MFMA + gelu ----
        f32x4 c0 = __builtin_amdgcn_mfma_f32_16x16x32_bf16(a1, b1f[0], zc, 0, 0, 0);
        f32x4 c1 = __builtin_amdgcn_mfma_f32_16x16x32_bf16(a1, b1f[1], zc, 0, 0, 0);
        #pragma unroll
        for (int r = 0; r < 4; ++r) {
            h_lds[wid][(q * 4 + r) * EGD + c15]      = f2bf(gelu_f(c0[r] + b1c0));
            h_lds[wid][(q * 4 + r) * EGD + 16 + c15] = f2bf(gelu_f(c1[r] + b1c1));
        }
        #pragma unroll
        for (int i = 0; i < 4; ++i)
            *(bf16x8*)&vsm[wid][srow * VSTRIDE + ssub * 32 + i * 8] = vreg[i];
        asm volatile("s_waitcnt lgkmcnt(0)" ::: "memory");
        __builtin_amdgcn_sched_barrier(0);
        // ---- layer-2 MFMA + fold ----
        const bf16x8 a2 = *(const bf16x8*)&h_lds[wid][c15 * EGD + q * 8];
        f32x4 at[4];
        #pragma unroll
        for (int r = 0; r < 4; ++r)
            at[r] = *(const f32x4*)&attn_lds[wid][q * 4 + r][0];
        f32x4 g[8];
        #pragma unroll
        for (int tt = 0; tt < 8; ++tt)
            g[tt] = __builtin_amdgcn_mfma_f32_16x16x32_bf16(a2, b2[tt], zc, 0, 0, 0);
        #pragma unroll
        for (int tt = 0; tt < 8; ++tt) {
            #pragma unroll
            for (int r = 0; r < 4; ++r) {
                const float sg = sigmoid_fast(g[tt][r] + bg2[tt]);
                const float aw = (tt < 2) ? at[r][0] : (tt < 4) ? at[r][1]
                               : (tt < 6) ? at[r][2] : at[r][3];
                const float vv = bf2f(vsm[wid][(q * 4 + r) * VSTRIDE + tt * 16 + c15]);
                accv[tt] = fmaf(aw * sg, vv, accv[tt]);
            }
        }
    }
    #pragma unroll
    for (int tt = 0; tt < 8; ++tt) {
        accv[tt] += __shfl_xor(accv[tt], 16);
        accv[tt] += __shfl_xor(accv[tt], 32);
    }
    aggb[(size_t)n * HID + (2 * q) * 16 + c15]     = (unsigned short)f2bf(accv[2 * q]);
    aggb[(size_t)n * HID + (2 * q + 1) * 16 + c15] = (unsigned short)f2bf(accv[2 * q + 1]);
}

// ---------------- K5: Wo + FiLM + residual + LN2 + FFN + residual, via MFMA ----------------
__global__ void __launch_bounds__(256) k5_out(
    const unsigned short* __restrict__ aggb, const unsigned short* __restrict__ Wom,
    const float* __restrict__ bo,
    const float* __restrict__ gamma, const float* __restrict__ beta,
    const float* __restrict__ x,
    const float* __restrict__ g2, const float* __restrict__ b2,
    const unsigned short* __restrict__ Wf1m, const float* __restrict__ bf1,
    const unsigned short* __restrict__ Wf2m, const float* __restrict__ bf2,
    float* __restrict__ out)
{
    __shared__ float xlsm[16][HID];
    __shared__ __align__(16) unsigned short xnb[16 * HID];
    __shared__ __align__(16) unsigned short hb[16 * 2 * HID];
    const int t = threadIdx.x;
    const int base = blockIdx.x * 16;
    const int w = t >> 6, l = t & 63, q = l >> 4, c15 = l & 15;
    const f32x4 zc = {0.f, 0.f, 0.f, 0.f};

    bf16x8 a[4];
    #pragma unroll
    for (int kc = 0; kc < 4; ++kc)
        a[kc] = *(const bf16x8*)(aggb + (size_t)(base + c15) * HID + kc * 32 + q * 8);
    float xl[2][4];
    #pragma unroll
    for (int ct = 0; ct < 2; ++ct) {
        const int colb = (w * 2 + ct) * 16;
        f32x4 acc = zc;
        #pragma unroll
        for (int kc = 0; kc < 4; ++kc)
            acc = __builtin_amdgcn_mfma_f32_16x16x32_bf16(
                a[kc], *(const bf16x8*)(Wom + (size_t)((kc * 4 + q) * HID + colb + c15) * 8), acc, 0, 0, 0);
        const float bov = bo[colb + c15];
        #pragma unroll
        for (int r = 0; r < 4; ++r) {
            const int row = q * 4 + r;
            const size_t idx = (size_t)(base + row) * HID + colb + c15;
            float o = acc[r] + bov;
            o = fmaf(gamma[idx], o, beta[idx]);
            const float v = x[idx] + o;
            xl[ct][r] = v;
            xlsm[row][colb + c15] = v;
        }
    }
    __syncthreads();
    {
        const int sr = t >> 4, sl = t & 15;
        float s1 = 0.f, s2 = 0.f, v[8];
        #pragma unroll
        for (int j = 0; j < 8; ++j) { v[j] = xlsm[sr][sl + 16 * j]; s1 += v[j]; s2 += v[j] * v[j]; }
        #pragma unroll
        for (int m = 1; m < 16; m <<= 1) { s1 += __shfl_xor(s1, m); s2 += __shfl_xor(s2, m); }
        const float mu = s1 * (1.0f / HID);
        const float rstd = rsqrtf(s2 * (1.0f / HID) - mu * mu + 1e-5f);
        char* rowp = (char*)(xnb + sr * HID);
        #pragma unroll
        for (int j = 0; j < 8; ++j) {
            const int col = sl + 16 * j;
            const float nv = (v[j] - mu) * rstd * g2[col] + b2[col];
            *(unsigned short*)(rowp + ((col * 2) ^ ((sr & 7) << 4))) = (unsigned short)f2bf(nv);
        }
    }
    __syncthreads();
    {
        const char* rowp = (const char*)(xnb + c15 * HID);
        bf16x8 a2[4];
        #pragma unroll
        for (int kc = 0; kc < 4; ++kc)
            a2[kc] = *(const bf16x8*)(rowp + ((kc * 64 + q * 16) ^ ((c15 & 7) << 4)));
        #pragma unroll
        for (int ct = 0; ct < 4; ++ct) {
            const int colb = (w * 4 + ct) * 16;
            f32x4 acc = zc;
            #pragma unroll
            for (int kc = 0; kc < 4; ++kc)
                acc = __builtin_amdgcn_mfma_f32_16x16x32_bf16(
                    a2[kc], *(const bf16x8*)(Wf1m + (size_t)((kc * 4 + q) * 256 + colb + c15) * 8), acc, 0, 0, 0);
            const float b1v = bf1[colb + c15];
            #pragma unroll
            for (int r = 0; r < 4; ++r) {
                const int row = q * 4 + r;
                const float hg = gelu_f(acc[r] + b1v);
                *(unsigned short*)((char*)(hb + row * 2 * HID)
                    + (((colb + c15) * 2) ^ ((row & 7) << 4))) = (unsigned short)f2bf(hg);
            }
        }
    }
    __syncthreads();
    {
        const char* rowp = (const char*)(hb + c15 * 2 * HID);
        bf16x8 a3[8];
        #pragma unroll
        for (int kc = 0; kc < 8; ++kc)
            a3[kc] = *(const bf16x8*)(rowp + ((kc * 64 + q * 16) ^ ((c15 & 7) << 4)));
        #pragma unroll
        for (int ct = 0; ct < 2; ++ct) {
            const int colb = (w * 2 + ct) * 16;
            f32x4 acc = zc;
            #pragma unroll
            for (int kc = 0; kc < 8; ++kc)
                acc = __builtin_amdgcn_mfma_f32_16x16x32_bf16(
                    a3[kc], *(const bf16x8*)(Wf2m + (size_t)((kc * 4 + q) * HID + colb + c15) * 8), acc, 0, 0, 0);
            const float b2v = bf2[colb + c15];
            #pragma unroll
            for (int r = 0; r < 4; ++r) {
                const int row = q * 4 + r;
                out[(size_t)(base + row) * HID + colb + c15] = xl[ct][r] + acc[r] + b2v;
            }
        }
    }
}

extern "C" void kernel_launch(void* const* d_in, const int* in_sizes, int n_in,
                              void* d_out, int out_size, void* d_ws, size_t ws_size,
                              hipStream_t stream) {
    const float* x     = (const float*)d_in[0];
    const int*   ei    = (const int*)d_in[1];
    const float* ea    = (const float*)d_in[2];
    const float* gamma = (const float*)d_in[3];
    const float* beta  = (const float*)d_in[4];
    const float* ln1_g = (const float*)d_in[5];
    const float* ln1_b = (const float*)d_in[6];
    const float* Wq    = (const float*)d_in[7];
    const float* Wk    = (const float*)d_in[8];
    const float* Wv    = (const float*)d_in[9];
    const float* Wo    = (const float*)d_in[10];
    const float* bo    = (const float*)d_in[11];
    const float* Wea1  = (const float*)d_in[12];
    const float* bea1  = (const float*)d_in[13];
    const float* Wea2  = (const float*)d_in[14];
    const float* bea2  = (const float*)d_in[15];
    const float* Weg1  = (const float*)d_in[16];
    const float* beg1  = (const float*)d_in[17];
    const float* Weg2  = (const float*)d_in[18];
    const float* beg2  = (const float*)d_in[19];
    const float* ln2_g = (const float*)d_in[20];
    const float* ln2_b = (const float*)d_in[21];
    const float* Wf1   = (const float*)d_in[22];
    const float* bf1   = (const float*)d_in[23];
    const float* Wf2   = (const float*)d_in[24];
    const float* bf2   = (const float*)d_in[25];

    unsigned short* Qb   = (unsigned short*)d_ws;
    unsigned short* Kb   = Qb + (size_t)N_NODES * HID;
    unsigned short* Vb   = Kb + (size_t)N_NODES * HID;
    unsigned short* aggb = Vb + (size_t)N_NODES * HID;
    unsigned short* eab  = aggb + (size_t)N_NODES * HID;
    unsigned short* Wqm  = eab + (size_t)E_EDGES * EDIM;
    unsigned short* Wkm  = Wqm + 16384;
    unsigned short* Wvm  = Wkm + 16384;
    unsigned short* Wom  = Wvm + 16384;
    unsigned short* Wf1m = Wom + 16384;
    unsigned short* Wf2m = Wf1m + 32768;
    unsigned short* Wea1m = Wf2m + 32768;
    unsigned short* Wea2m = Wea1m + 1024;
    float* logits = (float*)(Wea2m + 512);
    float* mbuf   = logits + (size_t)E_EDGES * 4;
    int*   deg    = (int*)(mbuf + (size_t)N_NODES * 4);
    int*   rowptr = deg + N_NODES;
    int*   wptr   = rowptr + (N_NODES + 1);
    int*   bsum   = wptr + N_NODES;
    int*   eidx   = bsum + 128;
    int*   esrc   = eidx + E_EDGES;
    int*   pdst   = esrc + E_EDGES;

    // zero mbuf + deg (contiguous)
    hipMemsetAsync(mbuf, 0,
                   (size_t)N_NODES * 4 * sizeof(float) + (size_t)N_NODES * sizeof(int),
                   stream);

    k0w_conv<<<513, 256, 0, stream>>>(Wq, Wk, Wv, Wo, Wf1, Wf2, Wea1, Wea2,
                                      Wqm, Wkm, Wvm, Wom, Wf1m, Wf2m, Wea1m, Wea2m);

    // CSR build
    k0a_degree<<<E_EDGES / 256, 256, 0, stream>>>(ei, deg);
    k0b_scan1<<<SCAN_NB, SCAN_BS, 0, stream>>>(deg, rowptr, bsum);
    k0c_scan2<<<1, 128, 0, stream>>>(bsum);
    k0d_fixup<<<SCAN_NB, SCAN_BS, 0, stream>>>(rowptr, wptr, bsum);
    k0e_scatter<<<E_EDGES / 256, 256, 0, stream>>>(ei, wptr, eidx, esrc, pdst);

    k1_ln_qkv<<<N_NODES / 16, 256, 0, stream>>>(x, ln1_g, ln1_b, Wqm, Wkm, Wvm,
                                                Qb, Kb, Vb);
    k2_fused<<<E_EDGES / 64, 256, 0, stream>>>(eidx, esrc, pdst, Qb, Kb, ea,
                                               Wea1m, bea1, Wea2m, bea2,
                                               logits, mbuf, eab);
    k4_mfma<<<N_NODES / 4, 256, 0, stream>>>(rowptr, esrc, eab,
                                             Weg1, beg1, Weg2, beg2,
                                             logits, mbuf, Vb, aggb);
    k5_out<<<N_NODES / 16, 256, 0, stream>>>(aggb, Wom, bo, gamma, beta, x,
                                             ln2_g, ln2_b, Wf1m, bf1, Wf2m, bf2,
                                             (float*)d_out);
}

// Round 12
// 364.206 us; speedup vs baseline: 2.0292x; 1.0786x over previous
//
#include <hip/hip_runtime.h>
#include <cmath>

#define N_NODES 50000
#define E_EDGES 800000
#define HID 128
#define HEADS 4
#define EDIM 16
#define EGD 32
#define VSTRIDE 136   // ushorts per staged V row (272B, 16B-aligned rows)
#define SCAN_BS 512
#define SCAN_NB ((N_NODES + SCAN_BS - 1) / SCAN_BS)

typedef __attribute__((ext_vector_type(8))) short bf16x8;
typedef __attribute__((ext_vector_type(4))) float f32x4;

__device__ __forceinline__ float gelu_f(float z) {
    return 0.5f * z * (1.0f + erff(z * 0.7071067811865476f));
}
__device__ __forceinline__ float sigmoid_fast(float z) {
    return __builtin_amdgcn_rcpf(1.0f + __expf(-z));
}
__device__ __forceinline__ short f2bf(float f) {
    unsigned u = __float_as_uint(f);
    unsigned r = u + 0x7fffu + ((u >> 16) & 1u);
    return (short)(r >> 16);
}
__device__ __forceinline__ float bf2f(unsigned short u) {
    return __uint_as_float(((unsigned)u) << 16);
}

// ---------------- K0w: weights -> bf16 MFMA layouts ----------------
// Node GEMMs: pos(k,n)=((k>>3)*N+n)*8+(k&7).
// Edge-MLP frags: Wea1m/Wea2m (k2) and Wg1m/Wg2m (k4 gate).
__global__ void __launch_bounds__(256) k0w_conv(
    const float* __restrict__ Wq, const float* __restrict__ Wk, const float* __restrict__ Wv,
    const float* __restrict__ Wo, const float* __restrict__ Wf1, const float* __restrict__ Wf2,
    const float* __restrict__ Wea1, const float* __restrict__ Wea2,
    const float* __restrict__ Weg1, const float* __restrict__ Weg2,
    unsigned short* __restrict__ Wqm, unsigned short* __restrict__ Wkm,
    unsigned short* __restrict__ Wvm, unsigned short* __restrict__ Wom,
    unsigned short* __restrict__ Wf1m, unsigned short* __restrict__ Wf2m,
    unsigned short* __restrict__ Wea1m, unsigned short* __restrict__ Wea2m,
    unsigned short* __restrict__ Wg1m, unsigned short* __restrict__ Wg2m)
{
    const int b = blockIdx.x, t = threadIdx.x;
    if (b == 512) {
        for (int i = t; i < 1024; i += 256) {
            const int j = i & 7, rest = i >> 3;
            const int n = rest & 31, q = rest >> 5, k = q * 8 + j;
            Wea1m[i] = (unsigned short)((k < EDIM) ? f2bf(Wea1[k * EGD + n]) : (short)0);
        }
        for (int i = t; i < 512; i += 256) {
            const int j = i & 7, rest = i >> 3;
            const int n = rest & 15, q = rest >> 4, k = q * 8 + j;
            Wea2m[i] = (unsigned short)((n < HEADS) ? f2bf(Wea2[k * HEADS + n]) : (short)0);
        }
        // Wg1m: idx = ((q*2+n)*16+c15)*8+j ; zero-padded for q>=2
        for (int i = t; i < 1024; i += 256) {
            const int j = i & 7, rest = i >> 3;
            const int c15 = rest & 15, qn = rest >> 4;
            const int q = qn >> 1, n = qn & 1;
            const int k = q * 8 + j;
            Wg1m[i] = (unsigned short)((k < EDIM) ? f2bf(Weg1[k * EGD + n * 16 + c15]) : (short)0);
        }
        // Wg2m: idx = ((q*8+tt)*16+c15)*8+j
        for (int i = t; i < 4096; i += 256) {
            const int j = i & 7, rest = i >> 3;
            const int c15 = rest & 15, rest2 = rest >> 4;
            const int tt = rest2 & 7, q = rest2 >> 3;
            const int k = q * 8 + j;
            Wg2m[i] = (unsigned short)f2bf(Weg2[k * HID + tt * 16 + c15]);
        }
        return;
    }
    const float* src; unsigned short* dst; int idx; bool wide;
    if (b < 64)       { src = Wq;  dst = Wqm;  idx = b * 256 + t;         wide = false; }
    else if (b < 128) { src = Wk;  dst = Wkm;  idx = (b - 64) * 256 + t;  wide = false; }
    else if (b < 192) { src = Wv;  dst = Wvm;  idx = (b - 128) * 256 + t; wide = false; }
    else if (b < 256) { src = Wo;  dst = Wom;  idx = (b - 192) * 256 + t; wide = false; }
    else if (b < 384) { src = Wf1; dst = Wf1m; idx = (b - 256) * 256 + t; wide = true;  }
    else              { src = Wf2; dst = Wf2m; idx = (b - 384) * 256 + t; wide = false; }
    int k, n, N;
    if (wide) { k = idx >> 8; n = idx & 255; N = 256; }
    else      { k = idx >> 7; n = idx & 127; N = 128; }
    dst[((size_t)(k >> 3) * N + n) * 8 + (k & 7)] = (unsigned short)f2bf(src[idx]);
}

// ---------------- K1: LN1 + QKV via MFMA (16 rows / 256 threads) ----------------
// A: row=lane&15, k=(lane>>4)*8+j.  B: col=lane&15, k=(lane>>4)*8+j.  C/D: col=lane&15, row=(lane>>4)*4+reg.
__global__ void __launch_bounds__(256) k1_ln_qkv(
    const float* __restrict__ x, const float* __restrict__ g1, const float* __restrict__ b1,
    const unsigned short* __restrict__ Wqm, const unsigned short* __restrict__ Wkm,
    const unsigned short* __restrict__ Wvm,
    unsigned short* __restrict__ Qb, unsigned short* __restrict__ Kb,
    unsigned short* __restrict__ Vb)
{
    __shared__ float xsm[16][HID];
    __shared__ __align__(16) unsigned short xnb[16 * HID]; // bf16, XOR-swizzled rows
    const int t = threadIdx.x;
    const int base = blockIdx.x * 16;
    {
        const float4* src = (const float4*)(x + (size_t)base * HID);
        float4* dst = (float4*)xsm;
        dst[t] = src[t];
        dst[t + 256] = src[t + 256];
    }
    __syncthreads();
    {
        const int sr = t >> 4, sl = t & 15;
        float s1 = 0.f, s2 = 0.f, v[8];
        #pragma unroll
        for (int j = 0; j < 8; ++j) { v[j] = xsm[sr][sl + 16 * j]; s1 += v[j]; s2 += v[j] * v[j]; }
        #pragma unroll
        for (int m = 1; m < 16; m <<= 1) { s1 += __shfl_xor(s1, m); s2 += __shfl_xor(s2, m); }
        const float mu = s1 * (1.0f / HID);
        const float rstd = rsqrtf(s2 * (1.0f / HID) - mu * mu + 1e-5f);
        char* rowp = (char*)(xnb + sr * HID);
        #pragma unroll
        for (int j = 0; j < 8; ++j) {
            const int col = sl + 16 * j;
            const float nv = (v[j] - mu) * rstd * g1[col] + b1[col];
            *(unsigned short*)(rowp + ((col * 2) ^ ((sr & 7) << 4))) = (unsigned short)f2bf(nv);
        }
    }
    __syncthreads();
    const int w = t >> 6, l = t & 63, q = l >> 4, c15 = l & 15;
    bf16x8 a[4];
    {
        const char* rowp = (const char*)(xnb + c15 * HID);
        #pragma unroll
        for (int kc = 0; kc < 4; ++kc)
            a[kc] = *(const bf16x8*)(rowp + ((kc * 64 + q * 16) ^ ((c15 & 7) << 4)));
    }
    const f32x4 zc = {0.f, 0.f, 0.f, 0.f};
    #pragma unroll
    for (int ct = 0; ct < 2; ++ct) {
        const int colb = (w * 2 + ct) * 16;
        f32x4 aq = zc, ak = zc, av = zc;
        #pragma unroll
        for (int kc = 0; kc < 4; ++kc) {
            const size_t boff = (size_t)((kc * 4 + q) * HID + colb + c15) * 8;
            aq = __builtin_amdgcn_mfma_f32_16x16x32_bf16(a[kc], *(const bf16x8*)(Wqm + boff), aq, 0, 0, 0);
            ak = __builtin_amdgcn_mfma_f32_16x16x32_bf16(a[kc], *(const bf16x8*)(Wkm + boff), ak, 0, 0, 0);
            av = __builtin_amdgcn_mfma_f32_16x16x32_bf16(a[kc], *(const bf16x8*)(Wvm + boff), av, 0, 0, 0);
        }
        #pragma unroll
        for (int r = 0; r < 4; ++r) {
            const size_t idx = (size_t)(base + q * 4 + r) * HID + colb + c15;
            Qb[idx] = (unsigned short)f2bf(aq[r]);
            Kb[idx] = (unsigned short)f2bf(ak[r]);
            Vb[idx] = (unsigned short)f2bf(av[r]);
        }
    }
}

// ---------------- CSR build ----------------
__global__ void __launch_bounds__(256) k0a_degree(
    const int* __restrict__ ei, int* __restrict__ deg)
{
    const int e = blockIdx.x * 256 + threadIdx.x;
    atomicAdd(deg + ei[E_EDGES + e], 1);
}

__global__ void __launch_bounds__(SCAN_BS) k0b_scan1(
    const int* __restrict__ deg, int* __restrict__ rowptr, int* __restrict__ bsum)
{
    __shared__ int sm[SCAN_BS];
    const int t = threadIdx.x;
    const int i = blockIdx.x * SCAN_BS + t;
    const int v = (i < N_NODES) ? deg[i] : 0;
    sm[t] = v;
    __syncthreads();
    #pragma unroll
    for (int off = 1; off < SCAN_BS; off <<= 1) {
        int add = (t >= off) ? sm[t - off] : 0;
        __syncthreads();
        sm[t] += add;
        __syncthreads();
    }
    if (i < N_NODES) rowptr[i] = sm[t] - v;
    if (t == SCAN_BS - 1) bsum[blockIdx.x] = sm[t];
}

__global__ void __launch_bounds__(128) k0c_scan2(int* __restrict__ bsum)
{
    __shared__ int sm[128];
    const int t = threadIdx.x;
    const int v = (t < SCAN_NB) ? bsum[t] : 0;
    sm[t] = v;
    __syncthreads();
    #pragma unroll
    for (int off = 1; off < 128; off <<= 1) {
        int add = (t >= off) ? sm[t - off] : 0;
        __syncthreads();
        sm[t] += add;
        __syncthreads();
    }
    if (t < SCAN_NB) bsum[t] = sm[t] - v; // exclusive
}

__global__ void __launch_bounds__(SCAN_BS) k0d_fixup(
    int* __restrict__ rowptr, int* __restrict__ wptr, const int* __restrict__ bsum)
{
    const int i = blockIdx.x * SCAN_BS + threadIdx.x;
    if (i < N_NODES) {
        int r = rowptr[i] + bsum[blockIdx.x];
        rowptr[i] = r;
        wptr[i] = r;
    }
    if (i == 0) rowptr[N_NODES] = E_EDGES;
}

__global__ void __launch_bounds__(256) k0e_scatter(
    const int* __restrict__ ei, int* __restrict__ wptr,
    int* __restrict__ eidx, int* __restrict__ esrc, int* __restrict__ pdst)
{
    const int e = blockIdx.x * 256 + threadIdx.x;
    const int d = ei[E_EDGES + e];
    const int pos = atomicAdd(wptr + d, 1);
    eidx[pos] = e;
    esrc[pos] = ei[e];
    pdst[pos] = d;
}

// ---------------- K2: QK dots (16 lanes/edge) + bias MLP via MFMA (16 edges/wave) ----------------
__global__ void __launch_bounds__(256) k2_fused(
    const int* __restrict__ eidx, const int* __restrict__ esrc, const int* __restrict__ pdst,
    const unsigned short* __restrict__ Qb, const unsigned short* __restrict__ Kb,
    const float* __restrict__ ea,
    const unsigned short* __restrict__ Wea1m, const float* __restrict__ bea1,
    const unsigned short* __restrict__ Wea2m, const float* __restrict__ bea2,
    float* __restrict__ logits, float* __restrict__ mbuf,
    unsigned short* __restrict__ eab)
{
    __shared__ __align__(16) float dot_lds[4][16][4];   // per wave [edge][head]
    __shared__ __align__(16) short h_lds[4][16 * EGD];  // per wave [edge][hidden] bf16
    const int t = threadIdx.x;
    const int w = t >> 6, l = t & 63;
    const int p0 = blockIdx.x * 64 + w * 16;            // this wave's 16 CSR slots

    // ---- phase A: QK dots, 4 chunks x 4 edges, 16 lanes/edge ----
    {
        const int er = l >> 4;
        const int i = l & 15;
        const int head = i >> 2, part = i & 3;
        #pragma unroll
        for (int cc = 0; cc < 4; ++cc) {
            const int p = p0 + cc * 4 + er;
            const int dst = pdst[p], src = esrc[p];
            const bf16x8 qv = *(const bf16x8*)(Qb + (size_t)dst * HID + head * 32 + part * 8);
            const bf16x8 kv = *(const bf16x8*)(Kb + (size_t)src * HID + head * 32 + part * 8);
            float s = 0.f;
            #pragma unroll
            for (int j = 0; j < 8; ++j)
                s = fmaf(bf2f((unsigned short)qv[j]), bf2f((unsigned short)kv[j]), s);
            s += __shfl_xor(s, 1);
            s += __shfl_xor(s, 2);
            if (part == 0) dot_lds[w][cc * 4 + er][head] = s * 0.17677669529663689f;
        }
    }

    // ---- phase B: bias MLP via MFMA over this wave's 16 edges ----
    const int q = l >> 4, c15 = l & 15;
    bf16x8 a1 = {0, 0, 0, 0, 0, 0, 0, 0};
    if (q < 2) {
        const int e = eidx[p0 + c15];
        const float4 u0 = *(const float4*)(ea + (size_t)e * EDIM + q * 8);
        const float4 u1 = *(const float4*)(ea + (size_t)e * EDIM + q * 8 + 4);
        a1[0] = f2bf(u0.x); a1[1] = f2bf(u0.y); a1[2] = f2bf(u0.z); a1[3] = f2bf(u0.w);
        a1[4] = f2bf(u1.x); a1[5] = f2bf(u1.y); a1[6] = f2bf(u1.z); a1[7] = f2bf(u1.w);
        *(bf16x8*)(eab + (size_t)(p0 + c15) * EDIM + q * 8) = a1;  // emit p-order bf16 ea
    }
    const bf16x8 b1f0 = *(const bf16x8*)(Wea1m + (size_t)(q * 32 + c15) * 8);
    const bf16x8 b1f1 = *(const bf16x8*)(Wea1m + (size_t)(q * 32 + 16 + c15) * 8);
    const f32x4 zc = {0.f, 0.f, 0.f, 0.f};
    f32x4 c0 = __builtin_amdgcn_mfma_f32_16x16x32_bf16(a1, b1f0, zc, 0, 0, 0);
    f32x4 c1 = __builtin_amdgcn_mfma_f32_16x16x32_bf16(a1, b1f1, zc, 0, 0, 0);
    const float bb0 = bea1[c15], bb1 = bea1[16 + c15];
    #pragma unroll
    for (int r = 0; r < 4; ++r) {
        h_lds[w][(q * 4 + r) * EGD + c15]      = f2bf(gelu_f(c0[r] + bb0));
        h_lds[w][(q * 4 + r) * EGD + 16 + c15] = f2bf(gelu_f(c1[r] + bb1));
    }
    asm volatile("s_waitcnt lgkmcnt(0)" ::: "memory");
    __builtin_amdgcn_sched_barrier(0);
    const bf16x8 a2 = *(const bf16x8*)&h_lds[w][c15 * EGD + q * 8];
    const bf16x8 b2 = *(const bf16x8*)(Wea2m + (size_t)(q * 16 + c15) * 8);
    f32x4 d2 = __builtin_amdgcn_mfma_f32_16x16x32_bf16(a2, b2, zc, 0, 0, 0);
    if (c15 < 4) {
        const float be = bea2[c15];
        #pragma unroll
        for (int r = 0; r < 4; ++r) {
            const int edge = q * 4 + r;
            const int p = p0 + edge;
            const float lg = dot_lds[w][edge][c15] + d2[r] + be;
            logits[(size_t)p * 4 + c15] = lg;
            if (lg > 0.f) {
                const int dst = pdst[p];
                atomicMax((int*)mbuf + (size_t)dst * 4 + c15, __float_as_int(lg));
            }
        }
    }
}

// ---------------- K4: softmax + MFMA gate MLP + attn-V fold; 1 wave = 1 node ----------------
// Weight frags loaded per-chunk from L1-hot global (keeps VGPR < 64 for occupancy).
__global__ void __launch_bounds__(256, 8) k4_mfma(
    const int* __restrict__ rowptr, const int* __restrict__ esrc,
    const unsigned short* __restrict__ eab,
    const unsigned short* __restrict__ Wg1m, const float* __restrict__ beg1,
    const unsigned short* __restrict__ Wg2m, const float* __restrict__ beg2,
    const float* __restrict__ logits, const float* __restrict__ mbuf,
    const unsigned short* __restrict__ Vb, unsigned short* __restrict__ aggb)
{
    __shared__ __align__(16) short h_lds[4][16 * EGD];
    __shared__ __align__(16) float attn_lds[4][16][4];
    __shared__ __align__(16) unsigned short vsm[4][16 * VSTRIDE];
    const int t = threadIdx.x;
    const int wid = t >> 6, l = t & 63;
    const int q = l >> 4, c15 = l & 15;

    const float b1c0 = beg1[c15], b1c1 = beg1[16 + c15];
    float bg2[8];
    #pragma unroll
    for (int tt = 0; tt < 8; ++tt) bg2[tt] = beg2[tt * 16 + c15];

    const f32x4 zc = {0.f, 0.f, 0.f, 0.f};
    const int n = blockIdx.x * 4 + wid;
    const int pstart = rowptr[n], pend = rowptr[n + 1];

    // esrc preload: lane l holds edge pstart+l (covers deg<=64; fallback below)
    const int pidx = pstart + l;
    const int my_src = (pidx < pend) ? esrc[pidx] : 0;

    // ---- pass 1: softmax denominator ----
    const int slot = l >> 2, head = l & 3;
    const float m_l = mbuf[(size_t)n * 4 + head];
    float ssum = 0.f, el0 = 0.f;
    for (int pc = pstart; pc < pend; pc += 16) {
        const int cnt = min(16, pend - pc);
        float el = 0.f;
        if (slot < cnt) el = __expf(logits[(size_t)(pc + slot) * 4 + head] - m_l);
        if (pc == pstart) el0 = el;
        ssum += el;
    }
    ssum += __shfl_xor(ssum, 4);
    ssum += __shfl_xor(ssum, 8);
    ssum += __shfl_xor(ssum, 16);
    ssum += __shfl_xor(ssum, 32);
    const float invh = __builtin_amdgcn_rcpf(ssum + 1e-10f);

    float accv[8];
    #pragma unroll
    for (int tt = 0; tt < 8; ++tt) accv[tt] = 0.f;

    const int srow = l >> 2;
    const int ssub = l & 3;

    for (int pc = pstart; pc < pend; pc += 16) {
        const int cnt = min(16, pend - pc);
        // ---- V staging: srcrow via shfl of preloaded esrc ----
        const int sidx = (srow < cnt) ? srow : cnt - 1;
        const int rel = pc - pstart + sidx;
        const int srcrow = (rel < 64) ? __shfl(my_src, rel) : esrc[pc + sidx];
        bf16x8 vreg[4];
        #pragma unroll
        for (int i = 0; i < 4; ++i)
            vreg[i] = *(const bf16x8*)(Vb + (size_t)srcrow * HID + ssub * 32 + i * 8);
        // ---- attn staging: all 64 lanes, one value each ----
        const float el = (pc == pstart) ? el0
            : ((slot < cnt) ? __expf(logits[(size_t)(pc + slot) * 4 + head] - m_l) : 0.f);
        attn_lds[wid][slot][head] = el * invh;
        // ---- a1 (lanes q<2) ----
        bf16x8 a1 = {0, 0, 0, 0, 0, 0, 0, 0};
        if (q < 2 && c15 < cnt)
            a1 = *(const bf16x8*)(eab + (size_t)(pc + c15) * EDIM + q * 8);
        // ---- layer-1 MFMA (weights L1-hot) + gelu ----
        const bf16x8 b1f0 = *(const bf16x8*)(Wg1m + (size_t)((q * 2 + 0) * 16 + c15) * 8);
        const bf16x8 b1f1 = *(const bf16x8*)(Wg1m + (size_t)((q * 2 + 1) * 16 + c15) * 8);
        f32x4 c0 = __builtin_amdgcn_mfma_f32_16x16x32_bf16(a1, b1f0, zc, 0, 0, 0);
        f32x4 c1 = __builtin_amdgcn_mfma_f32_16x16x32_bf16(a1, b1f1, zc, 0, 0, 0);
        #pragma unroll
        for (int r = 0; r < 4; ++r) {
            h_lds[wid][(q * 4 + r) * EGD + c15]      = f2bf(gelu_f(c0[r] + b1c0));
            h_lds[wid][(q * 4 + r) * EGD + 16 + c15] = f2bf(gelu_f(c1[r] + b1c1));
        }
        #pragma unroll
        for (int i = 0; i < 4; ++i)
            *(bf16x8*)&vsm[wid][srow * VSTRIDE + ssub * 32 + i * 8] = vreg[i];
        asm volatile("s_waitcnt lgkmcnt(0)" ::: "memory");
        __builtin_amdgcn_sched_barrier(0);
        // ---- layer-2 MFMA (weights L1-hot) + fold ----
        const bf16x8 a2 = *(const bf16x8*)&h_lds[wid][c15 * EGD + q * 8];
        f32x4 at[4];
        #pragma unroll
        for (int r = 0; r < 4; ++r)
            at[r] = *(const f32x4*)&attn_lds[wid][q * 4 + r][0];
        f32x4 g[8];
        #pragma unroll
        for (int tt = 0; tt < 8; ++tt) {
            const bf16x8 b2 = *(const bf16x8*)(Wg2m + (size_t)((q * 8 + tt) * 16 + c15) * 8);
            g[tt] = __builtin_amdgcn_mfma_f32_16x16x32_bf16(a2, b2, zc, 0, 0, 0);
        }
        #pragma unroll
        for (int tt = 0; tt < 8; ++tt) {
            #pragma unroll
            for (int r = 0; r < 4; ++r) {
                const float sg = sigmoid_fast(g[tt][r] + bg2[tt]);
                const float aw = (tt < 2) ? at[r][0] : (tt < 4) ? at[r][1]
                               : (tt < 6) ? at[r][2] : at[r][3];
                const float vv = bf2f(vsm[wid][(q * 4 + r) * VSTRIDE + tt * 16 + c15]);
                accv[tt] = fmaf(aw * sg, vv, accv[tt]);
            }
        }
    }
    #pragma unroll
    for (int tt = 0; tt < 8; ++tt) {
        accv[tt] += __shfl_xor(accv[tt], 16);
        accv[tt] += __shfl_xor(accv[tt], 32);
    }
    aggb[(size_t)n * HID + (2 * q) * 16 + c15]     = (unsigned short)f2bf(accv[2 * q]);
    aggb[(size_t)n * HID + (2 * q + 1) * 16 + c15] = (unsigned short)f2bf(accv[2 * q + 1]);
}

// ---------------- K5: Wo + FiLM + residual + LN2 + FFN + residual, via MFMA ----------------
__global__ void __launch_bounds__(256) k5_out(
    const unsigned short* __restrict__ aggb, const unsigned short* __restrict__ Wom,
    const float* __restrict__ bo,
    const float* __restrict__ gamma, const float* __restrict__ beta,
    const float* __restrict__ x,
    const float* __restrict__ g2, const float* __restrict__ b2,
    const unsigned short* __restrict__ Wf1m, const float* __restrict__ bf1,
    const unsigned short* __restrict__ Wf2m, const float* __restrict__ bf2,
    float* __restrict__ out)
{
    __shared__ float xlsm[16][HID];
    __shared__ __align__(16) unsigned short xnb[16 * HID];
    __shared__ __align__(16) unsigned short hb[16 * 2 * HID];
    const int t = threadIdx.x;
    const int base = blockIdx.x * 16;
    const int w = t >> 6, l = t & 63, q = l >> 4, c15 = l & 15;
    const f32x4 zc = {0.f, 0.f, 0.f, 0.f};

    bf16x8 a[4];
    #pragma unroll
    for (int kc = 0; kc < 4; ++kc)
        a[kc] = *(const bf16x8*)(aggb + (size_t)(base + c15) * HID + kc * 32 + q * 8);
    float xl[2][4];
    #pragma unroll
    for (int ct = 0; ct < 2; ++ct) {
        const int colb = (w * 2 + ct) * 16;
        f32x4 acc = zc;
        #pragma unroll
        for (int kc = 0; kc < 4; ++kc)
            acc = __builtin_amdgcn_mfma_f32_16x16x32_bf16(
                a[kc], *(const bf16x8*)(Wom + (size_t)((kc * 4 + q) * HID + colb + c15) * 8), acc, 0, 0, 0);
        const float bov = bo[colb + c15];
        #pragma unroll
        for (int r = 0; r < 4; ++r) {
            const int row = q * 4 + r;
            const size_t idx = (size_t)(base + row) * HID + colb + c15;
            float o = acc[r] + bov;
            o = fmaf(gamma[idx], o, beta[idx]);
            const float v = x[idx] + o;
            xl[ct][r] = v;
            xlsm[row][colb + c15] = v;
        }
    }
    __syncthreads();
    {
        const int sr = t >> 4, sl = t & 15;
        float s1 = 0.f, s2 = 0.f, v[8];
        #pragma unroll
        for (int j = 0; j < 8; ++j) { v[j] = xlsm[sr][sl + 16 * j]; s1 += v[j]; s2 += v[j] * v[j]; }
        #pragma unroll
        for (int m = 1; m < 16; m <<= 1) { s1 += __shfl_xor(s1, m); s2 += __shfl_xor(s2, m); }
        const float mu = s1 * (1.0f / HID);
        const float rstd = rsqrtf(s2 * (1.0f / HID) - mu * mu + 1e-5f);
        char* rowp = (char*)(xnb + sr * HID);
        #pragma unroll
        for (int j = 0; j < 8; ++j) {
            const int col = sl + 16 * j;
            const float nv = (v[j] - mu) * rstd * g2[col] + b2[col];
            *(unsigned short*)(rowp + ((col * 2) ^ ((sr & 7) << 4))) = (unsigned short)f2bf(nv);
        }
    }
    __syncthreads();
    {
        const char* rowp = (const char*)(xnb + c15 * HID);
        bf16x8 a2[4];
        #pragma unroll
        for (int kc = 0; kc < 4; ++kc)
            a2[kc] = *(const bf16x8*)(rowp + ((kc * 64 + q * 16) ^ ((c15 & 7) << 4)));
        #pragma unroll
        for (int ct = 0; ct < 4; ++ct) {
            const int colb = (w * 4 + ct) * 16;
            f32x4 acc = zc;
            #pragma unroll
            for (int kc = 0; kc < 4; ++kc)
                acc = __builtin_amdgcn_mfma_f32_16x16x32_bf16(
                    a2[kc], *(const bf16x8*)(Wf1m + (size_t)((kc * 4 + q) * 256 + colb + c15) * 8), acc, 0, 0, 0);
            const float b1v = bf1[colb + c15];
            #pragma unroll
            for (int r = 0; r < 4; ++r) {
                const int row = q * 4 + r;
                const float hg = gelu_f(acc[r] + b1v);
                *(unsigned short*)((char*)(hb + row * 2 * HID)
                    + (((colb + c15) * 2) ^ ((row & 7) << 4))) = (unsigned short)f2bf(hg);
            }
        }
    }
    __syncthreads();
    {
        const char* rowp = (const char*)(hb + c15 * 2 * HID);
        bf16x8 a3[8];
        #pragma unroll
        for (int kc = 0; kc < 8; ++kc)
            a3[kc] = *(const bf16x8*)(rowp + ((kc * 64 + q * 16) ^ ((c15 & 7) << 4)));
        #pragma unroll
        for (int ct = 0; ct < 2; ++ct) {
            const int colb = (w * 2 + ct) * 16;
            f32x4 acc = zc;
            #pragma unroll
            for (int kc = 0; kc < 8; ++kc)
                acc = __builtin_amdgcn_mfma_f32_16x16x32_bf16(
                    a3[kc], *(const bf16x8*)(Wf2m + (size_t)((kc * 4 + q) * HID + colb + c15) * 8), acc, 0, 0, 0);
            const float b2v = bf2[colb + c15];
            #pragma unroll
            for (int r = 0; r < 4; ++r) {
                const int row = q * 4 + r;
                out[(size_t)(base + row) * HID + colb + c15] = xl[ct][r] + acc[r] + b2v;
            }
        }
    }
}

extern "C" void kernel_launch(void* const* d_in, const int* in_sizes, int n_in,
                              void* d_out, int out_size, void* d_ws, size_t ws_size,
                              hipStream_t stream) {
    const float* x     = (const float*)d_in[0];
    const int*   ei    = (const int*)d_in[1];
    const float* ea    = (const float*)d_in[2];
    const float* gamma = (const float*)d_in[3];
    const float* beta  = (const float*)d_in[4];
    const float* ln1_g = (const float*)d_in[5];
    const float* ln1_b = (const float*)d_in[6];
    const float* Wq    = (const float*)d_in[7];
    const float* Wk    = (const float*)d_in[8];
    const float* Wv    = (const float*)d_in[9];
    const float* Wo    = (const float*)d_in[10];
    const float* bo    = (const float*)d_in[11];
    const float* Wea1  = (const float*)d_in[12];
    const float* bea1  = (const float*)d_in[13];
    const float* Wea2  = (const float*)d_in[14];
    const float* bea2  = (const float*)d_in[15];
    const float* Weg1  = (const float*)d_in[16];
    const float* beg1  = (const float*)d_in[17];
    const float* Weg2  = (const float*)d_in[18];
    const float* beg2  = (const float*)d_in[19];
    const float* ln2_g = (const float*)d_in[20];
    const float* ln2_b = (const float*)d_in[21];
    const float* Wf1   = (const float*)d_in[22];
    const float* bf1   = (const float*)d_in[23];
    const float* Wf2   = (const float*)d_in[24];
    const float* bf2   = (const float*)d_in[25];

    unsigned short* Qb   = (unsigned short*)d_ws;
    unsigned short* Kb   = Qb + (size_t)N_NODES * HID;
    unsigned short* Vb   = Kb + (size_t)N_NODES * HID;
    unsigned short* aggb = Vb + (size_t)N_NODES * HID;
    unsigned short* eab  = aggb + (size_t)N_NODES * HID;
    unsigned short* Wqm  = eab + (size_t)E_EDGES * EDIM;
    unsigned short* Wkm  = Wqm + 16384;
    unsigned short* Wvm  = Wkm + 16384;
    unsigned short* Wom  = Wvm + 16384;
    unsigned short* Wf1m = Wom + 16384;
    unsigned short* Wf2m = Wf1m + 32768;
    unsigned short* Wea1m = Wf2m + 32768;
    unsigned short* Wea2m = Wea1m + 1024;
    unsigned short* Wg1m  = Wea2m + 512;
    unsigned short* Wg2m  = Wg1m + 1024;
    float* logits = (float*)(Wg2m + 4096);
    float* mbuf   = logits + (size_t)E_EDGES * 4;
    int*   deg    = (int*)(mbuf + (size_t)N_NODES * 4);
    int*   rowptr = deg + N_NODES;
    int*   wptr   = rowptr + (N_NODES + 1);
    int*   bsum   = wptr + N_NODES;
    int*   eidx   = bsum + 128;
    int*   esrc   = eidx + E_EDGES;
    int*   pdst   = esrc + E_EDGES;

    // zero mbuf + deg (contiguous)
    hipMemsetAsync(mbuf, 0,
                   (size_t)N_NODES * 4 * sizeof(float) + (size_t)N_NODES * sizeof(int),
                   stream);

    k0w_conv<<<513, 256, 0, stream>>>(Wq, Wk, Wv, Wo, Wf1, Wf2, Wea1, Wea2, Weg1, Weg2,
                                      Wqm, Wkm, Wvm, Wom, Wf1m, Wf2m, Wea1m, Wea2m,
                                      Wg1m, Wg2m);

    // CSR build
    k0a_degree<<<E_EDGES / 256, 256, 0, stream>>>(ei, deg);
    k0b_scan1<<<SCAN_NB, SCAN_BS, 0, stream>>>(deg, rowptr, bsum);
    k0c_scan2<<<1, 128, 0, stream>>>(bsum);
    k0d_fixup<<<SCAN_NB, SCAN_BS, 0, stream>>>(rowptr, wptr, bsum);
    k0e_scatter<<<E_EDGES / 256, 256, 0, stream>>>(ei, wptr, eidx, esrc, pdst);

    k1_ln_qkv<<<N_NODES / 16, 256, 0, stream>>>(x, ln1_g, ln1_b, Wqm, Wkm, Wvm,
                                                Qb, Kb, Vb);
    k2_fused<<<E_EDGES / 64, 256, 0, stream>>>(eidx, esrc, pdst, Qb, Kb, ea,
                                               Wea1m, bea1, Wea2m, bea2,
                                               logits, mbuf, eab);
    k4_mfma<<<N_NODES / 4, 256, 0, stream>>>(rowptr, esrc, eab,
                                             Wg1m, beg1, Wg2m, beg2,
                                             logits, mbuf, Vb, aggb);
    k5_out<<<N_NODES / 16, 256, 0, stream>>>(aggb, Wom, bo, gamma, beta, x,
                                             ln2_g, ln2_b, Wf1m, bf1, Wf2m, bf2,
                                             (float*)d_out);
}

// Round 13
// 336.892 us; speedup vs baseline: 2.1937x; 1.0811x over previous
//
#include <hip/hip_runtime.h>
#include <cmath>

#define N_NODES 50000
#define E_EDGES 800000
#define HID 128
#define HEADS 4
#define EDIM 16
#define EGD 32
#define VSTRIDE 136   // ushorts per staged V row (272B, 16B-aligned rows)
#define SCAN_BS 512
#define SCAN_NB ((N_NODES + SCAN_BS - 1) / SCAN_BS)

typedef __attribute__((ext_vector_type(8))) short bf16x8;
typedef __attribute__((ext_vector_type(4))) float f32x4;

// Abramowitz-Stegun 7.1.26 erf: ~12 ops, max abs err 1.5e-7
__device__ __forceinline__ float erf_fast(float x) {
    const float ax = fabsf(x);
    const float t = __builtin_amdgcn_rcpf(fmaf(0.3275911f, ax, 1.0f));
    float p = fmaf(1.061405429f, t, -1.453152027f);
    p = fmaf(p, t, 1.421413741f);
    p = fmaf(p, t, -0.284496736f);
    p = fmaf(p, t, 0.254829592f);
    p = p * t;
    const float e = __expf(-ax * ax);
    const float r = fmaf(-p, e, 1.0f);
    return copysignf(r, x);
}
__device__ __forceinline__ float gelu_f(float z) {
    return 0.5f * z * (1.0f + erf_fast(z * 0.7071067811865476f));
}
__device__ __forceinline__ float sigmoid_fast(float z) {
    return __builtin_amdgcn_rcpf(1.0f + __expf(-z));
}
__device__ __forceinline__ short f2bf(float f) {
    unsigned u = __float_as_uint(f);
    unsigned r = u + 0x7fffu + ((u >> 16) & 1u);
    return (short)(r >> 16);
}
__device__ __forceinline__ float bf2f(unsigned short u) {
    return __uint_as_float(((unsigned)u) << 16);
}

// ---------------- K0w: weights -> bf16 MFMA layouts ----------------
// Node GEMMs: pos(k,n)=((k>>3)*N+n)*8+(k&7).
// Edge-MLP frags: Wea1m/Wea2m (k2) and Wg1m/Wg2m (k4 gate).
__global__ void __launch_bounds__(256) k0w_conv(
    const float* __restrict__ Wq, const float* __restrict__ Wk, const float* __restrict__ Wv,
    const float* __restrict__ Wo, const float* __restrict__ Wf1, const float* __restrict__ Wf2,
    const float* __restrict__ Wea1, const float* __restrict__ Wea2,
    const float* __restrict__ Weg1, const float* __restrict__ Weg2,
    unsigned short* __restrict__ Wqm, unsigned short* __restrict__ Wkm,
    unsigned short* __restrict__ Wvm, unsigned short* __restrict__ Wom,
    unsigned short* __restrict__ Wf1m, unsigned short* __restrict__ Wf2m,
    unsigned short* __restrict__ Wea1m, unsigned short* __restrict__ Wea2m,
    unsigned short* __restrict__ Wg1m, unsigned short* __restrict__ Wg2m)
{
    const int b = blockIdx.x, t = threadIdx.x;
    if (b == 512) {
        for (int i = t; i < 1024; i += 256) {
            const int j = i & 7, rest = i >> 3;
            const int n = rest & 31, q = rest >> 5, k = q * 8 + j;
            Wea1m[i] = (unsigned short)((k < EDIM) ? f2bf(Wea1[k * EGD + n]) : (short)0);
        }
        for (int i = t; i < 512; i += 256) {
            const int j = i & 7, rest = i >> 3;
            const int n = rest & 15, q = rest >> 4, k = q * 8 + j;
            Wea2m[i] = (unsigned short)((n < HEADS) ? f2bf(Wea2[k * HEADS + n]) : (short)0);
        }
        // Wg1m: idx = ((q*2+n)*16+c15)*8+j ; zero-padded for q>=2
        for (int i = t; i < 1024; i += 256) {
            const int j = i & 7, rest = i >> 3;
            const int c15 = rest & 15, qn = rest >> 4;
            const int q = qn >> 1, n = qn & 1;
            const int k = q * 8 + j;
            Wg1m[i] = (unsigned short)((k < EDIM) ? f2bf(Weg1[k * EGD + n * 16 + c15]) : (short)0);
        }
        // Wg2m: idx = ((q*8+tt)*16+c15)*8+j
        for (int i = t; i < 4096; i += 256) {
            const int j = i & 7, rest = i >> 3;
            const int c15 = rest & 15, rest2 = rest >> 4;
            const int tt = rest2 & 7, q = rest2 >> 3;
            const int k = q * 8 + j;
            Wg2m[i] = (unsigned short)f2bf(Weg2[k * HID + tt * 16 + c15]);
        }
        return;
    }
    const float* src; unsigned short* dst; int idx; bool wide;
    if (b < 64)       { src = Wq;  dst = Wqm;  idx = b * 256 + t;         wide = false; }
    else if (b < 128) { src = Wk;  dst = Wkm;  idx = (b - 64) * 256 + t;  wide = false; }
    else if (b < 192) { src = Wv;  dst = Wvm;  idx = (b - 128) * 256 + t; wide = false; }
    else if (b < 256) { src = Wo;  dst = Wom;  idx = (b - 192) * 256 + t; wide = false; }
    else if (b < 384) { src = Wf1; dst = Wf1m; idx = (b - 256) * 256 + t; wide = true;  }
    else              { src = Wf2; dst = Wf2m; idx = (b - 384) * 256 + t; wide = false; }
    int k, n, N;
    if (wide) { k = idx >> 8; n = idx & 255; N = 256; }
    else      { k = idx >> 7; n = idx & 127; N = 128; }
    dst[((size_t)(k >> 3) * N + n) * 8 + (k & 7)] = (unsigned short)f2bf(src[idx]);
}

// ---------------- K1: LN1 + QKV via MFMA (16 rows / 256 threads) ----------------
// A: row=lane&15, k=(lane>>4)*8+j.  B: col=lane&15, k=(lane>>4)*8+j.  C/D: col=lane&15, row=(lane>>4)*4+reg.
__global__ void __launch_bounds__(256) k1_ln_qkv(
    const float* __restrict__ x, const float* __restrict__ g1, const float* __restrict__ b1,
    const unsigned short* __restrict__ Wqm, const unsigned short* __restrict__ Wkm,
    const unsigned short* __restrict__ Wvm,
    unsigned short* __restrict__ Qb, unsigned short* __restrict__ Kb,
    unsigned short* __restrict__ Vb)
{
    __shared__ float xsm[16][HID];
    __shared__ __align__(16) unsigned short xnb[16 * HID]; // bf16, XOR-swizzled rows
    const int t = threadIdx.x;
    const int base = blockIdx.x * 16;
    {
        const float4* src = (const float4*)(x + (size_t)base * HID);
        float4* dst = (float4*)xsm;
        dst[t] = src[t];
        dst[t + 256] = src[t + 256];
    }
    __syncthreads();
    {
        const int sr = t >> 4, sl = t & 15;
        float s1 = 0.f, s2 = 0.f, v[8];
        #pragma unroll
        for (int j = 0; j < 8; ++j) { v[j] = xsm[sr][sl + 16 * j]; s1 += v[j]; s2 += v[j] * v[j]; }
        #pragma unroll
        for (int m = 1; m < 16; m <<= 1) { s1 += __shfl_xor(s1, m); s2 += __shfl_xor(s2, m); }
        const float mu = s1 * (1.0f / HID);
        const float rstd = rsqrtf(s2 * (1.0f / HID) - mu * mu + 1e-5f);
        char* rowp = (char*)(xnb + sr * HID);
        #pragma unroll
        for (int j = 0; j < 8; ++j) {
            const int col = sl + 16 * j;
            const float nv = (v[j] - mu) * rstd * g1[col] + b1[col];
            *(unsigned short*)(rowp + ((col * 2) ^ ((sr & 7) << 4))) = (unsigned short)f2bf(nv);
        }
    }
    __syncthreads();
    const int w = t >> 6, l = t & 63, q = l >> 4, c15 = l & 15;
    bf16x8 a[4];
    {
        const char* rowp = (const char*)(xnb + c15 * HID);
        #pragma unroll
        for (int kc = 0; kc < 4; ++kc)
            a[kc] = *(const bf16x8*)(rowp + ((kc * 64 + q * 16) ^ ((c15 & 7) << 4)));
    }
    const f32x4 zc = {0.f, 0.f, 0.f, 0.f};
    #pragma unroll
    for (int ct = 0; ct < 2; ++ct) {
        const int colb = (w * 2 + ct) * 16;
        f32x4 aq = zc, ak = zc, av = zc;
        #pragma unroll
        for (int kc = 0; kc < 4; ++kc) {
            const size_t boff = (size_t)((kc * 4 + q) * HID + colb + c15) * 8;
            aq = __builtin_amdgcn_mfma_f32_16x16x32_bf16(a[kc], *(const bf16x8*)(Wqm + boff), aq, 0, 0, 0);
            ak = __builtin_amdgcn_mfma_f32_16x16x32_bf16(a[kc], *(const bf16x8*)(Wkm + boff), ak, 0, 0, 0);
            av = __builtin_amdgcn_mfma_f32_16x16x32_bf16(a[kc], *(const bf16x8*)(Wvm + boff), av, 0, 0, 0);
        }
        #pragma unroll
        for (int r = 0; r < 4; ++r) {
            const size_t idx = (size_t)(base + q * 4 + r) * HID + colb + c15;
            Qb[idx] = (unsigned short)f2bf(aq[r]);
            Kb[idx] = (unsigned short)f2bf(ak[r]);
            Vb[idx] = (unsigned short)f2bf(av[r]);
        }
    }
}

// ---------------- CSR build ----------------
__global__ void __launch_bounds__(256) k0a_degree(
    const int* __restrict__ ei, int* __restrict__ deg)
{
    const int e = blockIdx.x * 256 + threadIdx.x;
    atomicAdd(deg + ei[E_EDGES + e], 1);
}

__global__ void __launch_bounds__(SCAN_BS) k0b_scan1(
    const int* __restrict__ deg, int* __restrict__ rowptr, int* __restrict__ bsum)
{
    __shared__ int sm[SCAN_BS];
    const int t = threadIdx.x;
    const int i = blockIdx.x * SCAN_BS + t;
    const int v = (i < N_NODES) ? deg[i] : 0;
    sm[t] = v;
    __syncthreads();
    #pragma unroll
    for (int off = 1; off < SCAN_BS; off <<= 1) {
        int add = (t >= off) ? sm[t - off] : 0;
        __syncthreads();
        sm[t] += add;
        __syncthreads();
    }
    if (i < N_NODES) rowptr[i] = sm[t] - v;
    if (t == SCAN_BS - 1) bsum[blockIdx.x] = sm[t];
}

__global__ void __launch_bounds__(128) k0c_scan2(int* __restrict__ bsum)
{
    __shared__ int sm[128];
    const int t = threadIdx.x;
    const int v = (t < SCAN_NB) ? bsum[t] : 0;
    sm[t] = v;
    __syncthreads();
    #pragma unroll
    for (int off = 1; off < 128; off <<= 1) {
        int add = (t >= off) ? sm[t - off] : 0;
        __syncthreads();
        sm[t] += add;
        __syncthreads();
    }
    if (t < SCAN_NB) bsum[t] = sm[t] - v; // exclusive
}

__global__ void __launch_bounds__(SCAN_BS) k0d_fixup(
    int* __restrict__ rowptr, int* __restrict__ wptr, const int* __restrict__ bsum)
{
    const int i = blockIdx.x * SCAN_BS + threadIdx.x;
    if (i < N_NODES) {
        int r = rowptr[i] + bsum[blockIdx.x];
        rowptr[i] = r;
        wptr[i] = r;
    }
    if (i == 0) rowptr[N_NODES] = E_EDGES;
}

__global__ void __launch_bounds__(256) k0e_scatter(
    const int* __restrict__ ei, int* __restrict__ wptr,
    int* __restrict__ eidx, int* __restrict__ esrc, int* __restrict__ pdst)
{
    const int e = blockIdx.x * 256 + threadIdx.x;
    const int d = ei[E_EDGES + e];
    const int pos = atomicAdd(wptr + d, 1);
    eidx[pos] = e;
    esrc[pos] = ei[e];
    pdst[pos] = d;
}

// ---------------- K2: QK dots (16 lanes/edge) + bias MLP via MFMA (16 edges/wave) ----------------
// No segment-max: softmax is shift-invariant; reference's m>=0 clamp cancels exactly.
__global__ void __launch_bounds__(256) k2_fused(
    const int* __restrict__ eidx, const int* __restrict__ esrc, const int* __restrict__ pdst,
    const unsigned short* __restrict__ Qb, const unsigned short* __restrict__ Kb,
    const float* __restrict__ ea,
    const unsigned short* __restrict__ Wea1m, const float* __restrict__ bea1,
    const unsigned short* __restrict__ Wea2m, const float* __restrict__ bea2,
    float* __restrict__ logits,
    unsigned short* __restrict__ eab)
{
    __shared__ __align__(16) float dot_lds[4][16][4];   // per wave [edge][head]
    __shared__ __align__(16) short h_lds[4][16 * EGD];  // per wave [edge][hidden] bf16
    const int t = threadIdx.x;
    const int w = t >> 6, l = t & 63;
    const int p0 = blockIdx.x * 64 + w * 16;            // this wave's 16 CSR slots

    // ---- phase A: QK dots, 4 chunks x 4 edges, 16 lanes/edge ----
    {
        const int er = l >> 4;
        const int i = l & 15;
        const int head = i >> 2, part = i & 3;
        #pragma unroll
        for (int cc = 0; cc < 4; ++cc) {
            const int p = p0 + cc * 4 + er;
            const int dst = pdst[p], src = esrc[p];
            const bf16x8 qv = *(const bf16x8*)(Qb + (size_t)dst * HID + head * 32 + part * 8);
            const bf16x8 kv = *(const bf16x8*)(Kb + (size_t)src * HID + head * 32 + part * 8);
            float s = 0.f;
            #pragma unroll
            for (int j = 0; j < 8; ++j)
                s = fmaf(bf2f((unsigned short)qv[j]), bf2f((unsigned short)kv[j]), s);
            s += __shfl_xor(s, 1);
            s += __shfl_xor(s, 2);
            if (part == 0) dot_lds[w][cc * 4 + er][head] = s * 0.17677669529663689f;
        }
    }

    // ---- phase B: bias MLP via MFMA over this wave's 16 edges ----
    const int q = l >> 4, c15 = l & 15;
    bf16x8 a1 = {0, 0, 0, 0, 0, 0, 0, 0};
    if (q < 2) {
        const int e = eidx[p0 + c15];
        const float4 u0 = *(const float4*)(ea + (size_t)e * EDIM + q * 8);
        const float4 u1 = *(const float4*)(ea + (size_t)e * EDIM + q * 8 + 4);
        a1[0] = f2bf(u0.x); a1[1] = f2bf(u0.y); a1[2] = f2bf(u0.z); a1[3] = f2bf(u0.w);
        a1[4] = f2bf(u1.x); a1[5] = f2bf(u1.y); a1[6] = f2bf(u1.z); a1[7] = f2bf(u1.w);
        *(bf16x8*)(eab + (size_t)(p0 + c15) * EDIM + q * 8) = a1;  // emit p-order bf16 ea
    }
    const bf16x8 b1f0 = *(const bf16x8*)(Wea1m + (size_t)(q * 32 + c15) * 8);
    const bf16x8 b1f1 = *(const bf16x8*)(Wea1m + (size_t)(q * 32 + 16 + c15) * 8);
    const f32x4 zc = {0.f, 0.f, 0.f, 0.f};
    f32x4 c0 = __builtin_amdgcn_mfma_f32_16x16x32_bf16(a1, b1f0, zc, 0, 0, 0);
    f32x4 c1 = __builtin_amdgcn_mfma_f32_16x16x32_bf16(a1, b1f1, zc, 0, 0, 0);
    const float bb0 = bea1[c15], bb1 = bea1[16 + c15];
    #pragma unroll
    for (int r = 0; r < 4; ++r) {
        h_lds[w][(q * 4 + r) * EGD + c15]      = f2bf(gelu_f(c0[r] + bb0));
        h_lds[w][(q * 4 + r) * EGD + 16 + c15] = f2bf(gelu_f(c1[r] + bb1));
    }
    asm volatile("s_waitcnt lgkmcnt(0)" ::: "memory");
    __builtin_amdgcn_sched_barrier(0);
    const bf16x8 a2 = *(const bf16x8*)&h_lds[w][c15 * EGD + q * 8];
    const bf16x8 b2 = *(const bf16x8*)(Wea2m + (size_t)(q * 16 + c15) * 8);
    f32x4 d2 = __builtin_amdgcn_mfma_f32_16x16x32_bf16(a2, b2, zc, 0, 0, 0);
    if (c15 < 4) {
        const float be = bea2[c15];
        #pragma unroll
        for (int r = 0; r < 4; ++r) {
            const int edge = q * 4 + r;
            const int p = p0 + edge;
            logits[(size_t)p * 4 + c15] = dot_lds[w][edge][c15] + d2[r] + be;
        }
    }
}

// ---------------- K4: softmax + MFMA gate MLP + attn-V fold; 1 wave = 1 node ----------------
// Weight frags loaded per-chunk from L1-hot global (keeps VGPR < 64 for occupancy).
__global__ void __launch_bounds__(256, 8) k4_mfma(
    const int* __restrict__ rowptr, const int* __restrict__ esrc,
    const unsigned short* __restrict__ eab,
    const unsigned short* __restrict__ Wg1m, const float* __restrict__ beg1,
    const unsigned short* __restrict__ Wg2m, const float* __restrict__ beg2,
    const float* __restrict__ logits,
    const unsigned short* __restrict__ Vb, unsigned short* __restrict__ aggb)
{
    __shared__ __align__(16) short h_lds[4][16 * EGD];
    __shared__ __align__(16) float attn_lds[4][16][4];
    __shared__ __align__(16) unsigned short vsm[4][16 * VSTRIDE];
    const int t = threadIdx.x;
    const int wid = t >> 6, l = t & 63;
    const int q = l >> 4, c15 = l & 15;

    const float b1c0 = beg1[c15], b1c1 = beg1[16 + c15];
    float bg2[8];
    #pragma unroll
    for (int tt = 0; tt < 8; ++tt) bg2[tt] = beg2[tt * 16 + c15];

    const f32x4 zc = {0.f, 0.f, 0.f, 0.f};
    const int n = blockIdx.x * 4 + wid;
    const int pstart = rowptr[n], pend = rowptr[n + 1];

    // esrc preload: lane l holds edge pstart+l (covers deg<=64; fallback below)
    const int pidx = pstart + l;
    const int my_src = (pidx < pend) ? esrc[pidx] : 0;

    // ---- pass 1: softmax denominator (m = 0 by shift invariance) ----
    const int slot = l >> 2, head = l & 3;
    float ssum = 0.f, el0 = 0.f;
    for (int pc = pstart; pc < pend; pc += 16) {
        const int cnt = min(16, pend - pc);
        float el = 0.f;
        if (slot < cnt) el = __expf(logits[(size_t)(pc + slot) * 4 + head]);
        if (pc == pstart) el0 = el;
        ssum += el;
    }
    ssum += __shfl_xor(ssum, 4);
    ssum += __shfl_xor(ssum, 8);
    ssum += __shfl_xor(ssum, 16);
    ssum += __shfl_xor(ssum, 32);
    const float invh = __builtin_amdgcn_rcpf(ssum + 1e-10f);

    float accv[8];
    #pragma unroll
    for (int tt = 0; tt < 8; ++tt) accv[tt] = 0.f;

    const int srow = l >> 2;
    const int ssub = l & 3;

    for (int pc = pstart; pc < pend; pc += 16) {
        const int cnt = min(16, pend - pc);
        // ---- V staging: srcrow via shfl of preloaded esrc ----
        const int sidx = (srow < cnt) ? srow : cnt - 1;
        const int rel = pc - pstart + sidx;
        const int srcrow = (rel < 64) ? __shfl(my_src, rel) : esrc[pc + sidx];
        bf16x8 vreg[4];
        #pragma unroll
        for (int i = 0; i < 4; ++i)
            vreg[i] = *(const bf16x8*)(Vb + (size_t)srcrow * HID + ssub * 32 + i * 8);
        // ---- attn staging: all 64 lanes, one value each ----
        const float el = (pc == pstart) ? el0
            : ((slot < cnt) ? __expf(logits[(size_t)(pc + slot) * 4 + head]) : 0.f);
        attn_lds[wid][slot][head] = el * invh;
        // ---- a1 (lanes q<2) ----
        bf16x8 a1 = {0, 0, 0, 0, 0, 0, 0, 0};
        if (q < 2 && c15 < cnt)
            a1 = *(const bf16x8*)(eab + (size_t)(pc + c15) * EDIM + q * 8);
        // ---- layer-1 MFMA (weights L1-hot) + gelu ----
        const bf16x8 b1f0 = *(const bf16x8*)(Wg1m + (size_t)((q * 2 + 0) * 16 + c15) * 8);
        const bf16x8 b1f1 = *(const bf16x8*)(Wg1m + (size_t)((q * 2 + 1) * 16 + c15) * 8);
        f32x4 c0 = __builtin_amdgcn_mfma_f32_16x16x32_bf16(a1, b1f0, zc, 0, 0, 0);
        f32x4 c1 = __builtin_amdgcn_mfma_f32_16x16x32_bf16(a1, b1f1, zc, 0, 0, 0);
        #pragma unroll
        for (int r = 0; r < 4; ++r) {
            h_lds[wid][(q * 4 + r) * EGD + c15]      = f2bf(gelu_f(c0[r] + b1c0));
            h_lds[wid][(q * 4 + r) * EGD + 16 + c15] = f2bf(gelu_f(c1[r] + b1c1));
        }
        #pragma unroll
        for (int i = 0; i < 4; ++i)
            *(bf16x8*)&vsm[wid][srow * VSTRIDE + ssub * 32 + i * 8] = vreg[i];
        asm volatile("s_waitcnt lgkmcnt(0)" ::: "memory");
        __builtin_amdgcn_sched_barrier(0);
        // ---- layer-2 MFMA (weights L1-hot) + fold ----
        const bf16x8 a2 = *(const bf16x8*)&h_lds[wid][c15 * EGD + q * 8];
        f32x4 at[4];
        #pragma unroll
        for (int r = 0; r < 4; ++r)
            at[r] = *(const f32x4*)&attn_lds[wid][q * 4 + r][0];
        f32x4 g[8];
        #pragma unroll
        for (int tt = 0; tt < 8; ++tt) {
            const bf16x8 b2 = *(const bf16x8*)(Wg2m + (size_t)((q * 8 + tt) * 16 + c15) * 8);
            g[tt] = __builtin_amdgcn_mfma_f32_16x16x32_bf16(a2, b2, zc, 0, 0, 0);
        }
        #pragma unroll
        for (int tt = 0; tt < 8; ++tt) {
            #pragma unroll
            for (int r = 0; r < 4; ++r) {
                const float sg = sigmoid_fast(g[tt][r] + bg2[tt]);
                const float aw = (tt < 2) ? at[r][0] : (tt < 4) ? at[r][1]
                               : (tt < 6) ? at[r][2] : at[r][3];
                const float vv = bf2f(vsm[wid][(q * 4 + r) * VSTRIDE + tt * 16 + c15]);
                accv[tt] = fmaf(aw * sg, vv, accv[tt]);
            }
        }
    }
    #pragma unroll
    for (int tt = 0; tt < 8; ++tt) {
        accv[tt] += __shfl_xor(accv[tt], 16);
        accv[tt] += __shfl_xor(accv[tt], 32);
    }
    aggb[(size_t)n * HID + (2 * q) * 16 + c15]     = (unsigned short)f2bf(accv[2 * q]);
    aggb[(size_t)n * HID + (2 * q + 1) * 16 + c15] = (unsigned short)f2bf(accv[2 * q + 1]);
}

// ---------------- K5: Wo + FiLM + residual + LN2 + FFN + residual, via MFMA ----------------
__global__ void __launch_bounds__(256) k5_out(
    const unsigned short* __restrict__ aggb, const unsigned short* __restrict__ Wom,
    const float* __restrict__ bo,
    const float* __restrict__ gamma, const float* __restrict__ beta,
    const float* __restrict__ x,
    const float* __restrict__ g2, const float* __restrict__ b2,
    const unsigned short* __restrict__ Wf1m, const float* __restrict__ bf1,
    const unsigned short* __restrict__ Wf2m, const float* __restrict__ bf2,
    float* __restrict__ out)
{
    __shared__ float xlsm[16][HID];
    __shared__ __align__(16) unsigned short xnb[16 * HID];
    __shared__ __align__(16) unsigned short hb[16 * 2 * HID];
    const int t = threadIdx.x;
    const int base = blockIdx.x * 16;
    const int w = t >> 6, l = t & 63, q = l >> 4, c15 = l & 15;
    const f32x4 zc = {0.f, 0.f, 0.f, 0.f};

    bf16x8 a[4];
    #pragma unroll
    for (int kc = 0; kc < 4; ++kc)
        a[kc] = *(const bf16x8*)(aggb + (size_t)(base + c15) * HID + kc * 32 + q * 8);
    float xl[2][4];
    #pragma unroll
    for (int ct = 0; ct < 2; ++ct) {
        const int colb = (w * 2 + ct) * 16;
        f32x4 acc = zc;
        #pragma unroll
        for (int kc = 0; kc < 4; ++kc)
            acc = __builtin_amdgcn_mfma_f32_16x16x32_bf16(
                a[kc], *(const bf16x8*)(Wom + (size_t)((kc * 4 + q) * HID + colb + c15) * 8), acc, 0, 0, 0);
        const float bov = bo[colb + c15];
        #pragma unroll
        for (int r = 0; r < 4; ++r) {
            const int row = q * 4 + r;
            const size_t idx = (size_t)(base + row) * HID + colb + c15;
            float o = acc[r] + bov;
            o = fmaf(gamma[idx], o, beta[idx]);
            const float v = x[idx] + o;
            xl[ct][r] = v;
            xlsm[row][colb + c15] = v;
        }
    }
    __syncthreads();
    {
        const int sr = t >> 4, sl = t & 15;
        float s1 = 0.f, s2 = 0.f, v[8];
        #pragma unroll
        for (int j = 0; j < 8; ++j) { v[j] = xlsm[sr][sl + 16 * j]; s1 += v[j]; s2 += v[j] * v[j]; }
        #pragma unroll
        for (int m = 1; m < 16; m <<= 1) { s1 += __shfl_xor(s1, m); s2 += __shfl_xor(s2, m); }
        const float mu = s1 * (1.0f / HID);
        const float rstd = rsqrtf(s2 * (1.0f / HID) - mu * mu + 1e-5f);
        char* rowp = (char*)(xnb + sr * HID);
        #pragma unroll
        for (int j = 0; j < 8; ++j) {
            const int col = sl + 16 * j;
            const float nv = (v[j] - mu) * rstd * g2[col] + b2[col];
            *(unsigned short*)(rowp + ((col * 2) ^ ((sr & 7) << 4))) = (unsigned short)f2bf(nv);
        }
    }
    __syncthreads();
    {
        const char* rowp = (const char*)(xnb + c15 * HID);
        bf16x8 a2[4];
        #pragma unroll
        for (int kc = 0; kc < 4; ++kc)
            a2[kc] = *(const bf16x8*)(rowp + ((kc * 64 + q * 16) ^ ((c15 & 7) << 4)));
        #pragma unroll
        for (int ct = 0; ct < 4; ++ct) {
            const int colb = (w * 4 + ct) * 16;
            f32x4 acc = zc;
            #pragma unroll
            for (int kc = 0; kc < 4; ++kc)
                acc = __builtin_amdgcn_mfma_f32_16x16x32_bf16(
                    a2[kc], *(const bf16x8*)(Wf1m + (size_t)((kc * 4 + q) * 256 + colb + c15) * 8), acc, 0, 0, 0);
            const float b1v = bf1[colb + c15];
            #pragma unroll
            for (int r = 0; r < 4; ++r) {
                const int row = q * 4 + r;
                const float hg = gelu_f(acc[r] + b1v);
                *(unsigned short*)((char*)(hb + row * 2 * HID)
                    + (((colb + c15) * 2) ^ ((row & 7) << 4))) = (unsigned short)f2bf(hg);
            }
        }
    }
    __syncthreads();
    {
        const char* rowp = (const char*)(hb + c15 * 2 * HID);
        bf16x8 a3[8];
        #pragma unroll
        for (int kc = 0; kc < 8; ++kc)
            a3[kc] = *(const bf16x8*)(rowp + ((kc * 64 + q * 16) ^ ((c15 & 7) << 4)));
        #pragma unroll
        for (int ct = 0; ct < 2; ++ct) {
            const int colb = (w * 2 + ct) * 16;
            f32x4 acc = zc;
            #pragma unroll
            for (int kc = 0; kc < 8; ++kc)
                acc = __builtin_amdgcn_mfma_f32_16x16x32_bf16(
                    a3[kc], *(const bf16x8*)(Wf2m + (size_t)((kc * 4 + q) * HID + colb + c15) * 8), acc, 0, 0, 0);
            const float b2v = bf2[colb + c15];
            #pragma unroll
            for (int r = 0; r < 4; ++r) {
                const int row = q * 4 + r;
                out[(size_t)(base + row) * HID + colb + c15] = xl[ct][r] + acc[r] + b2v;
            }
        }
    }
}

extern "C" void kernel_launch(void* const* d_in, const int* in_sizes, int n_in,
                              void* d_out, int out_size, void* d_ws, size_t ws_size,
                              hipStream_t stream) {
    const float* x     = (const float*)d_in[0];
    const int*   ei    = (const int*)d_in[1];
    const float* ea    = (const float*)d_in[2];
    const float* gamma = (const float*)d_in[3];
    const float* beta  = (const float*)d_in[4];
    const float* ln1_g = (const float*)d_in[5];
    const float* ln1_b = (const float*)d_in[6];
    const float* Wq    = (const float*)d_in[7];
    const float* Wk    = (const float*)d_in[8];
    const float* Wv    = (const float*)d_in[9];
    const float* Wo    = (const float*)d_in[10];
    const float* bo    = (const float*)d_in[11];
    const float* Wea1  = (const float*)d_in[12];
    const float* bea1  = (const float*)d_in[13];
    const float* Wea2  = (const float*)d_in[14];
    const float* bea2  = (const float*)d_in[15];
    const float* Weg1  = (const float*)d_in[16];
    const float* beg1  = (const float*)d_in[17];
    const float* Weg2  = (const float*)d_in[18];
    const float* beg2  = (const float*)d_in[19];
    const float* ln2_g = (const float*)d_in[20];
    const float* ln2_b = (const float*)d_in[21];
    const float* Wf1   = (const float*)d_in[22];
    const float* bf1   = (const float*)d_in[23];
    const float* Wf2   = (const float*)d_in[24];
    const float* bf2   = (const float*)d_in[25];

    unsigned short* Qb   = (unsigned short*)d_ws;
    unsigned short* Kb   = Qb + (size_t)N_NODES * HID;
    unsigned short* Vb   = Kb + (size_t)N_NODES * HID;
    unsigned short* aggb = Vb + (size_t)N_NODES * HID;
    unsigned short* eab  = aggb + (size_t)N_NODES * HID;
    unsigned short* Wqm  = eab + (size_t)E_EDGES * EDIM;
    unsigned short* Wkm  = Wqm + 16384;
    unsigned short* Wvm  = Wkm + 16384;
    unsigned short* Wom  = Wvm + 16384;
    unsigned short* Wf1m = Wom + 16384;
    unsigned short* Wf2m = Wf1m + 32768;
    unsigned short* Wea1m = Wf2m + 32768;
    unsigned short* Wea2m = Wea1m + 1024;
    unsigned short* Wg1m  = Wea2m + 512;
    unsigned short* Wg2m  = Wg1m + 1024;
    float* logits = (float*)(Wg2m + 4096);
    int*   deg    = (int*)(logits + (size_t)E_EDGES * 4);
    int*   rowptr = deg + N_NODES;
    int*   wptr   = rowptr + (N_NODES + 1);
    int*   bsum   = wptr + N_NODES;
    int*   eidx   = bsum + 128;
    int*   esrc   = eidx + E_EDGES;
    int*   pdst   = esrc + E_EDGES;

    // zero deg
    hipMemsetAsync(deg, 0, (size_t)N_NODES * sizeof(int), stream);

    k0w_conv<<<513, 256, 0, stream>>>(Wq, Wk, Wv, Wo, Wf1, Wf2, Wea1, Wea2, Weg1, Weg2,
                                      Wqm, Wkm, Wvm, Wom, Wf1m, Wf2m, Wea1m, Wea2m,
                                      Wg1m, Wg2m);

    // CSR build
    k0a_degree<<<E_EDGES / 256, 256, 0, stream>>>(ei, deg);
    k0b_scan1<<<SCAN_NB, SCAN_BS, 0, stream>>>(deg, rowptr, bsum);
    k0c_scan2<<<1, 128, 0, stream>>>(bsum);
    k0d_fixup<<<SCAN_NB, SCAN_BS, 0, stream>>>(rowptr, wptr, bsum);
    k0e_scatter<<<E_EDGES / 256, 256, 0, stream>>>(ei, wptr, eidx, esrc, pdst);

    k1_ln_qkv<<<N_NODES / 16, 256, 0, stream>>>(x, ln1_g, ln1_b, Wqm, Wkm, Wvm,
                                                Qb, Kb, Vb);
    k2_fused<<<E_EDGES / 64, 256, 0, stream>>>(eidx, esrc, pdst, Qb, Kb, ea,
                                               Wea1m, bea1, Wea2m, bea2,
                                               logits, eab);
    k4_mfma<<<N_NODES / 4, 256, 0, stream>>>(rowptr, esrc, eab,
                                             Wg1m, beg1, Wg2m, beg2,
                                             logits, Vb, aggb);
    k5_out<<<N_NODES / 16, 256, 0, stream>>>(aggb, Wom, bo, gamma, beta, x,
                                             ln2_g, ln2_b, Wf1m, bf1, Wf2m, bf2,
                                             (float*)d_out);
}